// Round 1
// baseline (620.769 us; speedup 1.0000x reference)
//
#include <hip/hip_runtime.h>
#include <math.h>

#define S_LEN 256
#define BATCH 512
#define ROWS (S_LEN * BATCH)

// ---------------------------------------------------------------------------
// Setup kernel: reproduce numpy RandomState streams, build the fixed 16x16
// complex unitary M_g for each of the 4 gate layers (random layer + trainable
// ring).  64 threads: thread (g, col) simulates the circuit on basis state
// e_col and writes column col of M_g.
// Convention: wire w <-> bit (3-w) of the flat state index (row-major reshape).
// ---------------------------------------------------------------------------
__global__ void setup_kernel(const float* __restrict__ qrx,
                             const float* __restrict__ qry,
                             const float* __restrict__ qrz,
                             const float* __restrict__ qcrx,
                             float2* __restrict__ Mout) {
    __shared__ unsigned mt[624];
    __shared__ int   op_k [4][20];
    __shared__ int   op_w0[4][20];
    __shared__ int   op_w1[4][20];
    __shared__ float op_t [4][20];

    if (threadIdx.x == 0) {
        for (int seed = 0; seed < 4; ++seed) {
            // MT19937 init_genrand(seed)
            mt[0] = (unsigned)seed;
            for (int i = 1; i < 624; ++i)
                mt[i] = 1812433253u * (mt[i - 1] ^ (mt[i - 1] >> 30)) + (unsigned)i;
            int idx = 624;
            auto nextu = [&]() -> unsigned {
                if (idx >= 624) {
                    for (int i = 0; i < 624; ++i) {
                        unsigned y = (mt[i] & 0x80000000u) | (mt[(i + 1) % 624] & 0x7fffffffu);
                        mt[i] = mt[(i + 397) % 624] ^ (y >> 1) ^ ((y & 1u) ? 2567483615u : 0u);
                    }
                    idx = 0;
                }
                unsigned y = mt[idx++];
                y ^= y >> 11;
                y ^= (y << 7)  & 2636928640u;
                y ^= (y << 15) & 4022730752u;
                y ^= y >> 18;
                return y;
            };
            for (int o = 0; o < 20; ++o) {
                unsigned k = nextu() & 3u;          // randint(4): mask 3, no rejection
                if (k < 3u) {
                    int w = (int)(nextu() & 3u);    // randint(4)
                    unsigned A = nextu(), B = nextu();   // uniform(0, 2pi): rk_double
                    double d = ((double)(A >> 5) * 67108864.0 + (double)(B >> 6))
                               / 9007199254740992.0;
                    op_k[seed][o]  = (int)k;
                    op_w0[seed][o] = w;
                    op_w1[seed][o] = 0;
                    op_t[seed][o]  = (float)(6.283185307179586 * d);
                } else {
                    int w0 = (int)(nextu() & 3u);   // randint(4)
                    unsigned v;                      // randint(3): mask 3, reject >2
                    do { v = nextu() & 3u; } while (v > 2u);
                    op_k[seed][o]  = 3;
                    op_w0[seed][o] = w0;
                    op_w1[seed][o] = (int)((w0 + 1 + (int)v) & 3);
                    op_t[seed][o]  = 0.f;
                }
            }
        }
    }
    __syncthreads();

    int g   = threadIdx.x >> 4;
    int col = threadIdx.x & 15;

    float sr[16], si[16];
    for (int r = 0; r < 16; ++r) { sr[r] = (r == col) ? 1.f : 0.f; si[r] = 0.f; }

    auto ap1 = [&](int w, float g00r, float g00i, float g01r, float g01i,
                          float g10r, float g10i, float g11r, float g11i) {
        int m = 8 >> w;
        for (int r = 0; r < 16; ++r) {
            if (r & m) continue;
            int r1 = r | m;
            float ar = sr[r], ai = si[r], br = sr[r1], bi = si[r1];
            sr[r]  = g00r * ar - g00i * ai + g01r * br - g01i * bi;
            si[r]  = g00r * ai + g00i * ar + g01r * bi + g01i * br;
            sr[r1] = g10r * ar - g10i * ai + g11r * br - g11i * bi;
            si[r1] = g10r * ai + g10i * ar + g11r * bi + g11i * br;
        }
    };
    auto crx = [&](int w0, int w1, float c, float s) {
        // control w0 (=1 subspace), target w1; off-diag = -i*s
        int m0 = 8 >> w0, m1 = 8 >> w1;
        for (int r = 0; r < 16; ++r) {
            if ((r & m0) && !(r & m1)) {
                int r1 = r | m1;
                float ar = sr[r], ai = si[r], br = sr[r1], bi = si[r1];
                sr[r]  = c * ar + s * bi;  si[r]  = c * ai - s * br;
                sr[r1] = c * br + s * ai;  si[r1] = c * bi - s * ar;
            }
        }
    };

    // random layer
    for (int o = 0; o < 20; ++o) {
        int k = op_k[g][o];
        int w = op_w0[g][o];
        float t = op_t[g][o];
        float c = cosf(0.5f * t), s = sinf(0.5f * t);
        if (k == 0)      ap1(w, c, 0.f, 0.f, -s, 0.f, -s, c, 0.f);      // RX
        else if (k == 1) ap1(w, c, 0.f, -s, 0.f, s, 0.f, c, 0.f);       // RY
        else if (k == 2) ap1(w, c, -s, 0.f, 0.f, 0.f, 0.f, c, s);       // RZ
        else {                                                           // CNOT
            int m0 = 8 >> w, m1 = 8 >> op_w1[g][o];
            for (int r = 0; r < 16; ++r) {
                if ((r & m0) && !(r & m1)) {
                    int r1 = r | m1;
                    float tr = sr[r]; sr[r] = sr[r1]; sr[r1] = tr;
                    tr = si[r]; si[r] = si[r1]; si[r1] = tr;
                }
            }
        }
    }
    // trainable ring
    for (int w = 0; w < 4; ++w) {
        float t, c, s;
        t = qrx[g * 4 + w]; c = cosf(0.5f * t); s = sinf(0.5f * t);
        ap1(w, c, 0.f, 0.f, -s, 0.f, -s, c, 0.f);
        t = qry[g * 4 + w]; c = cosf(0.5f * t); s = sinf(0.5f * t);
        ap1(w, c, 0.f, -s, 0.f, s, 0.f, c, 0.f);
        t = qrz[g * 4 + w]; c = cosf(0.5f * t); s = sinf(0.5f * t);
        ap1(w, c, -s, 0.f, 0.f, 0.f, 0.f, c, s);
        t = qcrx[g * 4 + w]; c = cosf(0.5f * t); s = sinf(0.5f * t);
        crx(w, (w + 1) & 3, c, s);
    }

    for (int r = 0; r < 16; ++r)
        Mout[(g * 16 + r) * 16 + col] = make_float2(sr[r], si[r]);
}

// ---------------------------------------------------------------------------
// angx kernel: angx[row][g*4+q] = sum_d emb[tok[row], d] * lin_w[g,q,d] + lin_b
// Wave per row; lane = (chunk = l>>4 of 64 d's, q = l&15).  Weights are
// register-resident (fixed per lane across rows).
// ---------------------------------------------------------------------------
__global__ __launch_bounds__(256) void angx_kernel(const int* __restrict__ sent,
                                                   const float* __restrict__ emb,
                                                   const float* __restrict__ lin_w,
                                                   const float* __restrict__ lin_b,
                                                   float* __restrict__ angx) {
    int l  = threadIdx.x & 63;
    int q  = l & 15;
    int ch = l >> 4;
    int wid = (blockIdx.x * blockDim.x + threadIdx.x) >> 6;
    int nw  = (gridDim.x * blockDim.x) >> 6;

    const float* wr = lin_w + q * 260 + ch * 64;
    float w0[16], w1[16], w2[16], w3[16];
#pragma unroll
    for (int j = 0; j < 16; ++j) {
        float4 t = *(const float4*)(wr + j * 4);
        w0[j] = t.x; w1[j] = t.y; w2[j] = t.z; w3[j] = t.w;
    }
    float bias = lin_b[q];

    for (int row = wid; row < ROWS; row += nw) {
        int tok = sent[row];
        const float* er = emb + (size_t)tok * 256 + ch * 64;
        float acc = 0.f;
#pragma unroll
        for (int j = 0; j < 16; ++j) {
            float4 x = *(const float4*)(er + j * 4);
            acc = fmaf(x.x, w0[j], acc);
            acc = fmaf(x.y, w1[j], acc);
            acc = fmaf(x.z, w2[j], acc);
            acc = fmaf(x.w, w3[j], acc);
        }
        acc += __shfl_xor(acc, 16, 64);
        acc += __shfl_xor(acc, 32, 64);
        if (l < 16) angx[(size_t)row * 16 + q] = acc + bias;
    }
}

// ---------------------------------------------------------------------------
// Recurrence kernel: one wave per batch element.  Lane l: layer g = l>>4,
// state index r = l&15.  Per step: angles -> enc (rank-1) -> p_r = |M_g enc|^2
// -> Walsh butterfly gives <Z_w> -> activations -> LSTM update -> broadcast h.
// ---------------------------------------------------------------------------
__global__ __launch_bounds__(256) void lstm_kernel(const float* __restrict__ lin_w,
                                                   const float2* __restrict__ M,
                                                   const float* __restrict__ angx,
                                                   float* __restrict__ outs) {
    int l = threadIdx.x & 63;
    int b = (blockIdx.x * blockDim.x + threadIdx.x) >> 6;
    if (b >= BATCH) return;
    int g = l >> 4;
    int lw = l & 3;

    float mre[16], mim[16];
    const float2* rowp = M + ((g * 16) + (l & 15)) * 16;
#pragma unroll
    for (int j = 0; j < 16; ++j) { float2 v = rowp[j]; mre[j] = v.x; mim[j] = v.y; }

    float whh[4][4];
#pragma unroll
    for (int q = 0; q < 4; ++q)
#pragma unroll
        for (int w = 0; w < 4; ++w)
            whh[q][w] = lin_w[(g * 4 + q) * 260 + 256 + w];

    float h0 = 0.f, h1 = 0.f, h2 = 0.f, h3 = 0.f, cst = 0.f;
    int actsrc = (l & 48) | (8 >> lw);   // Walsh lane holding Z for (g, w=lw)
    int base4  = l & 60;

    for (int s = 0; s < S_LEN; ++s) {
        float4 ax = *(const float4*)(angx + (size_t)(s * BATCH + b) * 16 + g * 4);
        float a0 = ax.x + whh[0][0] * h0 + whh[0][1] * h1 + whh[0][2] * h2 + whh[0][3] * h3;
        float a1 = ax.y + whh[1][0] * h0 + whh[1][1] * h1 + whh[1][2] * h2 + whh[1][3] * h3;
        float a2 = ax.z + whh[2][0] * h0 + whh[2][1] * h1 + whh[2][2] * h2 + whh[2][3] * h3;
        float a3 = ax.w + whh[3][0] * h0 + whh[3][1] * h1 + whh[3][2] * h2 + whh[3][3] * h3;

        float ca0 = __cosf(0.5f * a0), sa0 = __sinf(0.5f * a0);
        float ca1 = __cosf(0.5f * a1), sa1 = __sinf(0.5f * a1);
        float ca2 = __cosf(0.5f * a2), sa2 = __sinf(0.5f * a2);
        float ca3 = __cosf(0.5f * a3), sa3 = __sinf(0.5f * a3);

        // enc[r]: wire w selects cos/sin by bit (3-w) of r
        float e0 = ca0 * ca1, e1 = ca0 * sa1, e2 = sa0 * ca1, e3 = sa0 * sa1;
        float t0 = ca2 * ca3, t1 = ca2 * sa3, t2 = sa2 * ca3, t3 = sa2 * sa3;
        float enc[16];
        enc[0]  = e0 * t0; enc[1]  = e0 * t1; enc[2]  = e0 * t2; enc[3]  = e0 * t3;
        enc[4]  = e1 * t0; enc[5]  = e1 * t1; enc[6]  = e1 * t2; enc[7]  = e1 * t3;
        enc[8]  = e2 * t0; enc[9]  = e2 * t1; enc[10] = e2 * t2; enc[11] = e2 * t3;
        enc[12] = e3 * t0; enc[13] = e3 * t1; enc[14] = e3 * t2; enc[15] = e3 * t3;

        float re = 0.f, im = 0.f;
#pragma unroll
        for (int j = 0; j < 16; ++j) {
            re = fmaf(mre[j], enc[j], re);
            im = fmaf(mim[j], enc[j], im);
        }
        float p = re * re + im * im;

        // Walsh-Hadamard butterfly over the 16-lane group
#pragma unroll
        for (int mm = 1; mm <= 8; mm <<= 1) {
            float o = __shfl_xor(p, mm, 64);
            p = (l & mm) ? (o - p) : (p + o);
        }

        // lane computes activation for (gate g, wire lw)
        float zin = __shfl(p, actsrc, 64);
        float kk = (g == 2) ? 2.f : 1.f;
        float sg = 1.f / (1.f + __expf(-kk * zin));
        float act = (g == 2) ? (2.f * sg - 1.f) : sg;

        float f  = __shfl(act, lw,      64);
        float ii = __shfl(act, 16 + lw, 64);
        float gg = __shfl(act, 32 + lw, 64);
        float oo = __shfl(act, 48 + lw, 64);

        cst = f * cst + ii * gg;
        float tn = 2.f / (1.f + __expf(-2.f * cst)) - 1.f;
        float hme = oo * tn;

        h0 = __shfl(hme, base4 | 0, 64);
        h1 = __shfl(hme, base4 | 1, 64);
        h2 = __shfl(hme, base4 | 2, 64);
        h3 = __shfl(hme, base4 | 3, 64);

        if (l < 4) outs[(size_t)(s * BATCH + b) * 4 + l] = hme;
    }
}

// ---------------------------------------------------------------------------
// logits + log_softmax: wave per (s,b) row, lane = tag.
// ---------------------------------------------------------------------------
__global__ __launch_bounds__(256) void logits_kernel(const float* __restrict__ outs,
                                                     const float* __restrict__ tag_w,
                                                     const float* __restrict__ tag_b,
                                                     float* __restrict__ out) {
    int l = threadIdx.x & 63;
    int wid = (blockIdx.x * blockDim.x + threadIdx.x) >> 6;
    int nw  = (gridDim.x * blockDim.x) >> 6;

    float4 w = *(const float4*)(tag_w + l * 4);
    float bb = tag_b[l];

    for (int row = wid; row < ROWS; row += nw) {
        float4 h = *(const float4*)(outs + (size_t)row * 4);
        float z = fmaf(h.x, w.x, fmaf(h.y, w.y, fmaf(h.z, w.z, fmaf(h.w, w.w, bb))));
        float m = z;
#pragma unroll
        for (int d = 1; d < 64; d <<= 1) m = fmaxf(m, __shfl_xor(m, d, 64));
        float e = __expf(z - m);
        float ssum = e;
#pragma unroll
        for (int d = 1; d < 64; d <<= 1) ssum += __shfl_xor(ssum, d, 64);
        out[(size_t)row * 64 + l] = (z - m) - __logf(ssum);
    }
}

// ---------------------------------------------------------------------------
extern "C" void kernel_launch(void* const* d_in, const int* in_sizes, int n_in,
                              void* d_out, int out_size, void* d_ws, size_t ws_size,
                              hipStream_t stream) {
    const int*   sent  = (const int*)d_in[0];
    const float* emb   = (const float*)d_in[1];
    const float* lin_w = (const float*)d_in[2];
    const float* lin_b = (const float*)d_in[3];
    const float* qrx   = (const float*)d_in[4];
    const float* qry   = (const float*)d_in[5];
    const float* qrz   = (const float*)d_in[6];
    const float* qcrx  = (const float*)d_in[7];
    const float* tag_w = (const float*)d_in[8];
    const float* tag_b = (const float*)d_in[9];
    float* out = (float*)d_out;

    char* ws = (char*)d_ws;
    float2* M    = (float2*)ws;                                   // 4*16*16*8 = 8 KB
    float*  angx = (float*)(ws + 8192);                           // ROWS*16*4 = 8 MB
    float*  outs = (float*)(ws + 8192 + (size_t)ROWS * 16 * 4);   // ROWS*4*4  = 2 MB

    setup_kernel<<<dim3(1), dim3(64), 0, stream>>>(qrx, qry, qrz, qcrx, M);
    angx_kernel<<<dim3(1024), dim3(256), 0, stream>>>(sent, emb, lin_w, lin_b, angx);
    lstm_kernel<<<dim3(128), dim3(256), 0, stream>>>(lin_w, M, angx, outs);
    logits_kernel<<<dim3(1024), dim3(256), 0, stream>>>(outs, tag_w, tag_b, out);
}

// Round 2
// 436.556 us; speedup vs baseline: 1.4220x; 1.4220x over previous
//
#include <hip/hip_runtime.h>
#include <math.h>

#define S_LEN 256
#define BATCH 512
#define ROWS (S_LEN * BATCH)

// ---------------------------------------------------------------------------
// Compile-time reproduction of np.random.RandomState(seed) op streams.
// Seeds are fixed (0..3), so the whole RAND_OPS table is a constexpr.
// Legacy randint(n): mask-and-reject; uniform(0,2pi): rk_double scaled.
// ---------------------------------------------------------------------------
struct MTState {
    unsigned mt[624];
    int idx;
    constexpr MTState(unsigned seed) : mt{}, idx(624) {
        mt[0] = seed;
        for (int i = 1; i < 624; ++i)
            mt[i] = 1812433253u * (mt[i - 1] ^ (mt[i - 1] >> 30)) + (unsigned)i;
    }
    constexpr unsigned next() {
        if (idx >= 624) {
            for (int i = 0; i < 624; ++i) {
                unsigned y = (mt[i] & 0x80000000u) | (mt[(i + 1) % 624] & 0x7fffffffu);
                mt[i] = mt[(i + 397) % 624] ^ (y >> 1) ^ ((y & 1u) ? 2567483615u : 0u);
            }
            idx = 0;
        }
        unsigned y = mt[idx++];
        y ^= y >> 11;
        y ^= (y << 7)  & 2636928640u;
        y ^= (y << 15) & 4022730752u;
        y ^= y >> 18;
        return y;
    }
};

struct OpsTab {
    int   k [4][20];
    int   w0[4][20];
    int   w1[4][20];
    float t [4][20];
};

constexpr OpsTab make_ops() {
    OpsTab o{};
    for (int seed = 0; seed < 4; ++seed) {
        MTState rng((unsigned)seed);
        for (int i = 0; i < 20; ++i) {
            unsigned k = rng.next() & 3u;            // randint(4)
            if (k < 3u) {
                int w = (int)(rng.next() & 3u);      // randint(4)
                unsigned A = rng.next(), B = rng.next();  // rk_double
                double d = ((double)(A >> 5) * 67108864.0 + (double)(B >> 6))
                           / 9007199254740992.0;
                o.k[seed][i]  = (int)k;
                o.w0[seed][i] = w;
                o.w1[seed][i] = 0;
                o.t[seed][i]  = (float)(6.283185307179586 * d);
            } else {
                int w0 = (int)(rng.next() & 3u);     // randint(4)
                unsigned v = rng.next() & 3u;        // randint(3): reject >2
                while (v > 2u) v = rng.next() & 3u;
                o.k[seed][i]  = 3;
                o.w0[seed][i] = w0;
                o.w1[seed][i] = (int)((w0 + 1 + (int)v) & 3);
                o.t[seed][i]  = 0.f;
            }
        }
    }
    return o;
}

__constant__ OpsTab OPS = make_ops();

// ---------------------------------------------------------------------------
// Setup kernel: build the fixed 16x16 complex unitary M_g for each gate layer
// (random layer + trainable ring).  64 threads: thread (g, col) simulates the
// circuit on basis state e_col and writes column col of M_g.
// Wire w <-> bit (3-w) of the flat state index (row-major reshape).
// ---------------------------------------------------------------------------
__global__ void setup_kernel(const float* __restrict__ qrx,
                             const float* __restrict__ qry,
                             const float* __restrict__ qrz,
                             const float* __restrict__ qcrx,
                             float2* __restrict__ Mout) {
    int g   = threadIdx.x >> 4;
    int col = threadIdx.x & 15;

    float sr[16], si[16];
    for (int r = 0; r < 16; ++r) { sr[r] = (r == col) ? 1.f : 0.f; si[r] = 0.f; }

    auto ap1 = [&](int w, float g00r, float g00i, float g01r, float g01i,
                          float g10r, float g10i, float g11r, float g11i) {
        int m = 8 >> w;
        for (int r = 0; r < 16; ++r) {
            if (r & m) continue;
            int r1 = r | m;
            float ar = sr[r], ai = si[r], br = sr[r1], bi = si[r1];
            sr[r]  = g00r * ar - g00i * ai + g01r * br - g01i * bi;
            si[r]  = g00r * ai + g00i * ar + g01r * bi + g01i * br;
            sr[r1] = g10r * ar - g10i * ai + g11r * br - g11i * bi;
            si[r1] = g10r * ai + g10i * ar + g11r * bi + g11i * br;
        }
    };
    auto crx = [&](int w0, int w1, float c, float s) {
        int m0 = 8 >> w0, m1 = 8 >> w1;
        for (int r = 0; r < 16; ++r) {
            if ((r & m0) && !(r & m1)) {
                int r1 = r | m1;
                float ar = sr[r], ai = si[r], br = sr[r1], bi = si[r1];
                sr[r]  = c * ar + s * bi;  si[r]  = c * ai - s * br;
                sr[r1] = c * br + s * ai;  si[r1] = c * bi - s * ar;
            }
        }
    };

    // random layer
    for (int o = 0; o < 20; ++o) {
        int k = OPS.k[g][o];
        int w = OPS.w0[g][o];
        float t = OPS.t[g][o];
        float c = cosf(0.5f * t), s = sinf(0.5f * t);
        if (k == 0)      ap1(w, c, 0.f, 0.f, -s, 0.f, -s, c, 0.f);      // RX
        else if (k == 1) ap1(w, c, 0.f, -s, 0.f, s, 0.f, c, 0.f);       // RY
        else if (k == 2) ap1(w, c, -s, 0.f, 0.f, 0.f, 0.f, c, s);       // RZ
        else {                                                           // CNOT
            int m0 = 8 >> w, m1 = 8 >> OPS.w1[g][o];
            for (int r = 0; r < 16; ++r) {
                if ((r & m0) && !(r & m1)) {
                    int r1 = r | m1;
                    float tr = sr[r]; sr[r] = sr[r1]; sr[r1] = tr;
                    tr = si[r]; si[r] = si[r1]; si[r1] = tr;
                }
            }
        }
    }
    // trainable ring
    for (int w = 0; w < 4; ++w) {
        float t, c, s;
        t = qrx[g * 4 + w]; c = cosf(0.5f * t); s = sinf(0.5f * t);
        ap1(w, c, 0.f, 0.f, -s, 0.f, -s, c, 0.f);
        t = qry[g * 4 + w]; c = cosf(0.5f * t); s = sinf(0.5f * t);
        ap1(w, c, 0.f, -s, 0.f, s, 0.f, c, 0.f);
        t = qrz[g * 4 + w]; c = cosf(0.5f * t); s = sinf(0.5f * t);
        ap1(w, c, -s, 0.f, 0.f, 0.f, 0.f, c, s);
        t = qcrx[g * 4 + w]; c = cosf(0.5f * t); s = sinf(0.5f * t);
        crx(w, (w + 1) & 3, c, s);
    }

    for (int r = 0; r < 16; ++r)
        Mout[(g * 16 + r) * 16 + col] = make_float2(sr[r], si[r]);
}

// ---------------------------------------------------------------------------
// angx kernel: angx[row][g*4+q] = sum_d emb[tok[row], d] * lin_w[g,q,d] + lin_b
// Wave per row; lane = (chunk = l>>4 of 64 d's, q = l&15).  Weights are
// register-resident (fixed per lane across rows).
// ---------------------------------------------------------------------------
__global__ __launch_bounds__(256) void angx_kernel(const int* __restrict__ sent,
                                                   const float* __restrict__ emb,
                                                   const float* __restrict__ lin_w,
                                                   const float* __restrict__ lin_b,
                                                   float* __restrict__ angx) {
    int l  = threadIdx.x & 63;
    int q  = l & 15;
    int ch = l >> 4;
    int wid = (blockIdx.x * blockDim.x + threadIdx.x) >> 6;
    int nw  = (gridDim.x * blockDim.x) >> 6;

    const float* wr = lin_w + q * 260 + ch * 64;
    float w0[16], w1[16], w2[16], w3[16];
#pragma unroll
    for (int j = 0; j < 16; ++j) {
        float4 t = *(const float4*)(wr + j * 4);
        w0[j] = t.x; w1[j] = t.y; w2[j] = t.z; w3[j] = t.w;
    }
    float bias = lin_b[q];

    for (int row = wid; row < ROWS; row += nw) {
        int tok = sent[row];
        const float* er = emb + (size_t)tok * 256 + ch * 64;
        float acc = 0.f;
#pragma unroll
        for (int j = 0; j < 16; ++j) {
            float4 x = *(const float4*)(er + j * 4);
            acc = fmaf(x.x, w0[j], acc);
            acc = fmaf(x.y, w1[j], acc);
            acc = fmaf(x.z, w2[j], acc);
            acc = fmaf(x.w, w3[j], acc);
        }
        acc += __shfl_xor(acc, 16, 64);
        acc += __shfl_xor(acc, 32, 64);
        if (l < 16) angx[(size_t)row * 16 + q] = acc + bias;
    }
}

// ---------------------------------------------------------------------------
// Recurrence kernel: one wave per batch element.  Lane l: layer g = l>>4,
// state index r = l&15.  Per step: angles -> enc (rank-1) -> p_r = |M_g enc|^2
// -> Walsh butterfly gives <Z_w> -> activations -> LSTM update -> broadcast h.
// ---------------------------------------------------------------------------
__global__ __launch_bounds__(256) void lstm_kernel(const float* __restrict__ lin_w,
                                                   const float2* __restrict__ M,
                                                   const float* __restrict__ angx,
                                                   float* __restrict__ outs) {
    int l = threadIdx.x & 63;
    int b = (blockIdx.x * blockDim.x + threadIdx.x) >> 6;
    if (b >= BATCH) return;
    int g = l >> 4;
    int lw = l & 3;

    float mre[16], mim[16];
    const float2* rowp = M + ((g * 16) + (l & 15)) * 16;
#pragma unroll
    for (int j = 0; j < 16; ++j) { float2 v = rowp[j]; mre[j] = v.x; mim[j] = v.y; }

    float whh[4][4];
#pragma unroll
    for (int q = 0; q < 4; ++q)
#pragma unroll
        for (int w = 0; w < 4; ++w)
            whh[q][w] = lin_w[(g * 4 + q) * 260 + 256 + w];

    float h0 = 0.f, h1 = 0.f, h2 = 0.f, h3 = 0.f, cst = 0.f;
    int actsrc = (l & 48) | (8 >> lw);   // Walsh lane holding Z for (g, w=lw)
    int base4  = l & 60;

    for (int s = 0; s < S_LEN; ++s) {
        float4 ax = *(const float4*)(angx + (size_t)(s * BATCH + b) * 16 + g * 4);
        float a0 = ax.x + whh[0][0] * h0 + whh[0][1] * h1 + whh[0][2] * h2 + whh[0][3] * h3;
        float a1 = ax.y + whh[1][0] * h0 + whh[1][1] * h1 + whh[1][2] * h2 + whh[1][3] * h3;
        float a2 = ax.z + whh[2][0] * h0 + whh[2][1] * h1 + whh[2][2] * h2 + whh[2][3] * h3;
        float a3 = ax.w + whh[3][0] * h0 + whh[3][1] * h1 + whh[3][2] * h2 + whh[3][3] * h3;

        float ca0 = __cosf(0.5f * a0), sa0 = __sinf(0.5f * a0);
        float ca1 = __cosf(0.5f * a1), sa1 = __sinf(0.5f * a1);
        float ca2 = __cosf(0.5f * a2), sa2 = __sinf(0.5f * a2);
        float ca3 = __cosf(0.5f * a3), sa3 = __sinf(0.5f * a3);

        // enc[r]: wire w selects cos/sin by bit (3-w) of r
        float e0 = ca0 * ca1, e1 = ca0 * sa1, e2 = sa0 * ca1, e3 = sa0 * sa1;
        float t0 = ca2 * ca3, t1 = ca2 * sa3, t2 = sa2 * ca3, t3 = sa2 * sa3;
        float enc[16];
        enc[0]  = e0 * t0; enc[1]  = e0 * t1; enc[2]  = e0 * t2; enc[3]  = e0 * t3;
        enc[4]  = e1 * t0; enc[5]  = e1 * t1; enc[6]  = e1 * t2; enc[7]  = e1 * t3;
        enc[8]  = e2 * t0; enc[9]  = e2 * t1; enc[10] = e2 * t2; enc[11] = e2 * t3;
        enc[12] = e3 * t0; enc[13] = e3 * t1; enc[14] = e3 * t2; enc[15] = e3 * t3;

        float re = 0.f, im = 0.f;
#pragma unroll
        for (int j = 0; j < 16; ++j) {
            re = fmaf(mre[j], enc[j], re);
            im = fmaf(mim[j], enc[j], im);
        }
        float p = re * re + im * im;

        // Walsh-Hadamard butterfly over the 16-lane group
#pragma unroll
        for (int mm = 1; mm <= 8; mm <<= 1) {
            float o = __shfl_xor(p, mm, 64);
            p = (l & mm) ? (o - p) : (p + o);
        }

        // lane computes activation for (gate g, wire lw)
        float zin = __shfl(p, actsrc, 64);
        float kk = (g == 2) ? 2.f : 1.f;
        float sg = 1.f / (1.f + __expf(-kk * zin));
        float act = (g == 2) ? (2.f * sg - 1.f) : sg;

        float f  = __shfl(act, lw,      64);
        float ii = __shfl(act, 16 + lw, 64);
        float gg = __shfl(act, 32 + lw, 64);
        float oo = __shfl(act, 48 + lw, 64);

        cst = f * cst + ii * gg;
        float tn = 2.f / (1.f + __expf(-2.f * cst)) - 1.f;
        float hme = oo * tn;

        h0 = __shfl(hme, base4 | 0, 64);
        h1 = __shfl(hme, base4 | 1, 64);
        h2 = __shfl(hme, base4 | 2, 64);
        h3 = __shfl(hme, base4 | 3, 64);

        if (l < 4) outs[(size_t)(s * BATCH + b) * 4 + l] = hme;
    }
}

// ---------------------------------------------------------------------------
// logits + log_softmax: wave per (s,b) row, lane = tag.
// ---------------------------------------------------------------------------
__global__ __launch_bounds__(256) void logits_kernel(const float* __restrict__ outs,
                                                     const float* __restrict__ tag_w,
                                                     const float* __restrict__ tag_b,
                                                     float* __restrict__ out) {
    int l = threadIdx.x & 63;
    int wid = (blockIdx.x * blockDim.x + threadIdx.x) >> 6;
    int nw  = (gridDim.x * blockDim.x) >> 6;

    float4 w = *(const float4*)(tag_w + l * 4);
    float bb = tag_b[l];

    for (int row = wid; row < ROWS; row += nw) {
        float4 h = *(const float4*)(outs + (size_t)row * 4);
        float z = fmaf(h.x, w.x, fmaf(h.y, w.y, fmaf(h.z, w.z, fmaf(h.w, w.w, bb))));
        float m = z;
#pragma unroll
        for (int d = 1; d < 64; d <<= 1) m = fmaxf(m, __shfl_xor(m, d, 64));
        float e = __expf(z - m);
        float ssum = e;
#pragma unroll
        for (int d = 1; d < 64; d <<= 1) ssum += __shfl_xor(ssum, d, 64);
        out[(size_t)row * 64 + l] = (z - m) - __logf(ssum);
    }
}

// ---------------------------------------------------------------------------
extern "C" void kernel_launch(void* const* d_in, const int* in_sizes, int n_in,
                              void* d_out, int out_size, void* d_ws, size_t ws_size,
                              hipStream_t stream) {
    const int*   sent  = (const int*)d_in[0];
    const float* emb   = (const float*)d_in[1];
    const float* lin_w = (const float*)d_in[2];
    const float* lin_b = (const float*)d_in[3];
    const float* qrx   = (const float*)d_in[4];
    const float* qry   = (const float*)d_in[5];
    const float* qrz   = (const float*)d_in[6];
    const float* qcrx  = (const float*)d_in[7];
    const float* tag_w = (const float*)d_in[8];
    const float* tag_b = (const float*)d_in[9];
    float* out = (float*)d_out;

    char* ws = (char*)d_ws;
    float2* M    = (float2*)ws;                                   // 4*16*16*8 = 8 KB
    float*  angx = (float*)(ws + 8192);                           // ROWS*16*4 = 8 MB
    float*  outs = (float*)(ws + 8192 + (size_t)ROWS * 16 * 4);   // ROWS*4*4  = 2 MB

    setup_kernel<<<dim3(1), dim3(64), 0, stream>>>(qrx, qry, qrz, qcrx, M);
    angx_kernel<<<dim3(1024), dim3(256), 0, stream>>>(sent, emb, lin_w, lin_b, angx);
    lstm_kernel<<<dim3(128), dim3(256), 0, stream>>>(lin_w, M, angx, outs);
    logits_kernel<<<dim3(1024), dim3(256), 0, stream>>>(outs, tag_w, tag_b, out);
}

// Round 3
// 382.342 us; speedup vs baseline: 1.6236x; 1.1418x over previous
//
#include <hip/hip_runtime.h>
#include <math.h>

#define S_LEN 256
#define BATCH 512
#define ROWS (S_LEN * BATCH)

// ---------------------------------------------------------------------------
// Compile-time reproduction of np.random.RandomState(seed) op streams.
// Seeds are fixed (0..3), so the whole RAND_OPS table is a constexpr.
// Legacy randint(n): mask-and-reject; uniform(0,2pi): rk_double scaled.
// ---------------------------------------------------------------------------
struct MTState {
    unsigned mt[624];
    int idx;
    constexpr MTState(unsigned seed) : mt{}, idx(624) {
        mt[0] = seed;
        for (int i = 1; i < 624; ++i)
            mt[i] = 1812433253u * (mt[i - 1] ^ (mt[i - 1] >> 30)) + (unsigned)i;
    }
    constexpr unsigned next() {
        if (idx >= 624) {
            for (int i = 0; i < 624; ++i) {
                unsigned y = (mt[i] & 0x80000000u) | (mt[(i + 1) % 624] & 0x7fffffffu);
                mt[i] = mt[(i + 397) % 624] ^ (y >> 1) ^ ((y & 1u) ? 2567483615u : 0u);
            }
            idx = 0;
        }
        unsigned y = mt[idx++];
        y ^= y >> 11;
        y ^= (y << 7)  & 2636928640u;
        y ^= (y << 15) & 4022730752u;
        y ^= y >> 18;
        return y;
    }
};

struct OpsTab {
    int   k [4][20];
    int   w0[4][20];
    int   w1[4][20];
    float t [4][20];
};

constexpr OpsTab make_ops() {
    OpsTab o{};
    for (int seed = 0; seed < 4; ++seed) {
        MTState rng((unsigned)seed);
        for (int i = 0; i < 20; ++i) {
            unsigned k = rng.next() & 3u;            // randint(4)
            if (k < 3u) {
                int w = (int)(rng.next() & 3u);      // randint(4)
                unsigned A = rng.next(), B = rng.next();  // rk_double
                double d = ((double)(A >> 5) * 67108864.0 + (double)(B >> 6))
                           / 9007199254740992.0;
                o.k[seed][i]  = (int)k;
                o.w0[seed][i] = w;
                o.w1[seed][i] = 0;
                o.t[seed][i]  = (float)(6.283185307179586 * d);
            } else {
                int w0 = (int)(rng.next() & 3u);     // randint(4)
                unsigned v = rng.next() & 3u;        // randint(3): reject >2
                while (v > 2u) v = rng.next() & 3u;
                o.k[seed][i]  = 3;
                o.w0[seed][i] = w0;
                o.w1[seed][i] = (int)((w0 + 1 + (int)v) & 3);
                o.t[seed][i]  = 0.f;
            }
        }
    }
    return o;
}

constexpr OpsTab OPS_CE = make_ops();

// ---------------------------------------------------------------------------
// Fully-unrolled circuit fold: every state-array index is compile-time so
// sr[]/si[] stay in VGPRs (rule #20: runtime-indexed arrays go to scratch).
// Wire w <-> bit (3-w) of the flat state index (row-major reshape).
// ---------------------------------------------------------------------------
template <int M>
__device__ inline void gate1(float (&sr)[16], float (&si)[16],
                             float g00r, float g00i, float g01r, float g01i,
                             float g10r, float g10i, float g11r, float g11i) {
#pragma unroll
    for (int r = 0; r < 16; ++r) {
        if (r & M) continue;
        const int r1 = r | M;
        float ar = sr[r], ai = si[r], br = sr[r1], bi = si[r1];
        sr[r]  = g00r * ar - g00i * ai + g01r * br - g01i * bi;
        si[r]  = g00r * ai + g00i * ar + g01r * bi + g01i * br;
        sr[r1] = g10r * ar - g10i * ai + g11r * br - g11i * bi;
        si[r1] = g10r * ai + g10i * ar + g11r * bi + g11i * br;
    }
}

template <int G, int O>
__device__ inline void apply_rand_ops(float (&sr)[16], float (&si)[16]) {
    if constexpr (O < 20) {
        constexpr int   k = OPS_CE.k[G][O];
        constexpr int   w = OPS_CE.w0[G][O];
        constexpr float t = OPS_CE.t[G][O];
        constexpr int   M = 8 >> w;
        if constexpr (k == 3) {
            constexpr int M1 = 8 >> OPS_CE.w1[G][O];
#pragma unroll
            for (int r = 0; r < 16; ++r) {
                if ((r & M) && !(r & M1)) {
                    const int r1 = r | M1;
                    float tr = sr[r]; sr[r] = sr[r1]; sr[r1] = tr;
                    tr = si[r]; si[r] = si[r1]; si[r1] = tr;
                }
            }
        } else {
            float c = cosf(0.5f * t), s = sinf(0.5f * t);
            if constexpr (k == 0)       // RX
                gate1<M>(sr, si, c, 0.f, 0.f, -s, 0.f, -s, c, 0.f);
            else if constexpr (k == 1)  // RY
                gate1<M>(sr, si, c, 0.f, -s, 0.f, s, 0.f, c, 0.f);
            else                        // RZ
                gate1<M>(sr, si, c, -s, 0.f, 0.f, 0.f, 0.f, c, s);
        }
        apply_rand_ops<G, O + 1>(sr, si);
    }
}

template <int G, int W>
__device__ inline void ring_step(float (&sr)[16], float (&si)[16],
                                 const float* qrx, const float* qry,
                                 const float* qrz, const float* qcrx) {
    constexpr int M  = 8 >> W;
    constexpr int M1 = 8 >> ((W + 1) & 3);
    float t, c, s;
    t = qrx[G * 4 + W]; c = cosf(0.5f * t); s = sinf(0.5f * t);
    gate1<M>(sr, si, c, 0.f, 0.f, -s, 0.f, -s, c, 0.f);
    t = qry[G * 4 + W]; c = cosf(0.5f * t); s = sinf(0.5f * t);
    gate1<M>(sr, si, c, 0.f, -s, 0.f, s, 0.f, c, 0.f);
    t = qrz[G * 4 + W]; c = cosf(0.5f * t); s = sinf(0.5f * t);
    gate1<M>(sr, si, c, -s, 0.f, 0.f, 0.f, 0.f, c, s);
    t = qcrx[G * 4 + W]; c = cosf(0.5f * t); s = sinf(0.5f * t);
    // CRX: control M (=1 subspace), target M1; off-diag = -i*s
#pragma unroll
    for (int r = 0; r < 16; ++r) {
        if ((r & M) && !(r & M1)) {
            const int r1 = r | M1;
            float ar = sr[r], ai = si[r], br = sr[r1], bi = si[r1];
            sr[r]  = c * ar + s * bi;  si[r]  = c * ai - s * br;
            sr[r1] = c * br + s * ai;  si[r1] = c * bi - s * ar;
        }
    }
    if constexpr (W < 3) ring_step<G, W + 1>(sr, si, qrx, qry, qrz, qcrx);
}

template <int G>
__device__ inline void fold_circuit(int col, const float* qrx, const float* qry,
                                    const float* qrz, const float* qcrx,
                                    float2* Mout, bool writer) {
    float sr[16], si[16];
#pragma unroll
    for (int r = 0; r < 16; ++r) { sr[r] = (r == col) ? 1.f : 0.f; si[r] = 0.f; }

    apply_rand_ops<G, 0>(sr, si);
    ring_step<G, 0>(sr, si, qrx, qry, qrz, qcrx);

    if (writer) {
#pragma unroll
        for (int r = 0; r < 16; ++r)
            Mout[(G * 16 + r) * 16 + col] = make_float2(sr[r], si[r]);
    }
}

// 256 threads: wave w handles gate layer g=w (wave-uniform branch, no
// divergence); lanes replicate cols 0..15 four times, low group writes.
__global__ __launch_bounds__(256) void setup_kernel(const float* __restrict__ qrx,
                                                    const float* __restrict__ qry,
                                                    const float* __restrict__ qrz,
                                                    const float* __restrict__ qcrx,
                                                    float2* __restrict__ Mout) {
    int g   = threadIdx.x >> 6;
    int col = threadIdx.x & 15;
    bool wr = (threadIdx.x & 48) == 0;
    switch (g) {
        case 0: fold_circuit<0>(col, qrx, qry, qrz, qcrx, Mout, wr); break;
        case 1: fold_circuit<1>(col, qrx, qry, qrz, qcrx, Mout, wr); break;
        case 2: fold_circuit<2>(col, qrx, qry, qrz, qcrx, Mout, wr); break;
        case 3: fold_circuit<3>(col, qrx, qry, qrz, qcrx, Mout, wr); break;
    }
}

// ---------------------------------------------------------------------------
// angx kernel: angx[row][g*4+q] = sum_d emb[tok[row], d] * lin_w[g,q,d] + lin_b
// Wave per row; lane = (chunk = l>>4 of 64 d's, q = l&15).  Weights are
// register-resident (fixed per lane across rows).
// ---------------------------------------------------------------------------
__global__ __launch_bounds__(256) void angx_kernel(const int* __restrict__ sent,
                                                   const float* __restrict__ emb,
                                                   const float* __restrict__ lin_w,
                                                   const float* __restrict__ lin_b,
                                                   float* __restrict__ angx) {
    int l  = threadIdx.x & 63;
    int q  = l & 15;
    int ch = l >> 4;
    int wid = (blockIdx.x * blockDim.x + threadIdx.x) >> 6;
    int nw  = (gridDim.x * blockDim.x) >> 6;

    const float* wr = lin_w + q * 260 + ch * 64;
    float w0[16], w1[16], w2[16], w3[16];
#pragma unroll
    for (int j = 0; j < 16; ++j) {
        float4 t = *(const float4*)(wr + j * 4);
        w0[j] = t.x; w1[j] = t.y; w2[j] = t.z; w3[j] = t.w;
    }
    float bias = lin_b[q];

    for (int row = wid; row < ROWS; row += nw) {
        int tok = sent[row];
        const float* er = emb + (size_t)tok * 256 + ch * 64;
        float acc = 0.f;
#pragma unroll
        for (int j = 0; j < 16; ++j) {
            float4 x = *(const float4*)(er + j * 4);
            acc = fmaf(x.x, w0[j], acc);
            acc = fmaf(x.y, w1[j], acc);
            acc = fmaf(x.z, w2[j], acc);
            acc = fmaf(x.w, w3[j], acc);
        }
        acc += __shfl_xor(acc, 16, 64);
        acc += __shfl_xor(acc, 32, 64);
        if (l < 16) angx[(size_t)row * 16 + q] = acc + bias;
    }
}

// ---------------------------------------------------------------------------
// Recurrence kernel: one wave per batch element.  Lane l: layer g = l>>4,
// state index r = l&15.  Per step: angles -> enc (rank-1) -> p_r = |M_g enc|^2
// -> Walsh butterfly gives <Z_w> -> activations -> LSTM update -> broadcast h.
// ---------------------------------------------------------------------------
__global__ __launch_bounds__(256) void lstm_kernel(const float* __restrict__ lin_w,
                                                   const float2* __restrict__ M,
                                                   const float* __restrict__ angx,
                                                   float* __restrict__ outs) {
    int l = threadIdx.x & 63;
    int b = (blockIdx.x * blockDim.x + threadIdx.x) >> 6;
    if (b >= BATCH) return;
    int g = l >> 4;
    int lw = l & 3;

    float mre[16], mim[16];
    const float2* rowp = M + ((g * 16) + (l & 15)) * 16;
#pragma unroll
    for (int j = 0; j < 16; ++j) { float2 v = rowp[j]; mre[j] = v.x; mim[j] = v.y; }

    float whh[4][4];
#pragma unroll
    for (int q = 0; q < 4; ++q)
#pragma unroll
        for (int w = 0; w < 4; ++w)
            whh[q][w] = lin_w[(g * 4 + q) * 260 + 256 + w];

    float h0 = 0.f, h1 = 0.f, h2 = 0.f, h3 = 0.f, cst = 0.f;
    int actsrc = (l & 48) | (8 >> lw);   // Walsh lane holding Z for (g, w=lw)
    int base4  = l & 60;

    for (int s = 0; s < S_LEN; ++s) {
        float4 ax = *(const float4*)(angx + (size_t)(s * BATCH + b) * 16 + g * 4);
        float a0 = ax.x + whh[0][0] * h0 + whh[0][1] * h1 + whh[0][2] * h2 + whh[0][3] * h3;
        float a1 = ax.y + whh[1][0] * h0 + whh[1][1] * h1 + whh[1][2] * h2 + whh[1][3] * h3;
        float a2 = ax.z + whh[2][0] * h0 + whh[2][1] * h1 + whh[2][2] * h2 + whh[2][3] * h3;
        float a3 = ax.w + whh[3][0] * h0 + whh[3][1] * h1 + whh[3][2] * h2 + whh[3][3] * h3;

        float ca0 = __cosf(0.5f * a0), sa0 = __sinf(0.5f * a0);
        float ca1 = __cosf(0.5f * a1), sa1 = __sinf(0.5f * a1);
        float ca2 = __cosf(0.5f * a2), sa2 = __sinf(0.5f * a2);
        float ca3 = __cosf(0.5f * a3), sa3 = __sinf(0.5f * a3);

        // enc[r]: wire w selects cos/sin by bit (3-w) of r
        float e0 = ca0 * ca1, e1 = ca0 * sa1, e2 = sa0 * ca1, e3 = sa0 * sa1;
        float t0 = ca2 * ca3, t1 = ca2 * sa3, t2 = sa2 * ca3, t3 = sa2 * sa3;
        float enc[16];
        enc[0]  = e0 * t0; enc[1]  = e0 * t1; enc[2]  = e0 * t2; enc[3]  = e0 * t3;
        enc[4]  = e1 * t0; enc[5]  = e1 * t1; enc[6]  = e1 * t2; enc[7]  = e1 * t3;
        enc[8]  = e2 * t0; enc[9]  = e2 * t1; enc[10] = e2 * t2; enc[11] = e2 * t3;
        enc[12] = e3 * t0; enc[13] = e3 * t1; enc[14] = e3 * t2; enc[15] = e3 * t3;

        // tree-reduced complex dot (short dependent chain, static indices)
        float pr[16], pi[16];
#pragma unroll
        for (int j = 0; j < 16; ++j) { pr[j] = mre[j] * enc[j]; pi[j] = mim[j] * enc[j]; }
#pragma unroll
        for (int st = 8; st > 0; st >>= 1) {
#pragma unroll
            for (int j = 0; j < 16; ++j) {
                if (j < st) { pr[j] += pr[j + st]; pi[j] += pi[j + st]; }
            }
        }
        float p = pr[0] * pr[0] + pi[0] * pi[0];

        // Walsh-Hadamard butterfly over the 16-lane group
#pragma unroll
        for (int mm = 1; mm <= 8; mm <<= 1) {
            float o = __shfl_xor(p, mm, 64);
            p = (l & mm) ? (o - p) : (p + o);
        }

        // lane computes activation for (gate g, wire lw)
        float zin = __shfl(p, actsrc, 64);
        float kk = (g == 2) ? 2.f : 1.f;
        float sg = 1.f / (1.f + __expf(-kk * zin));
        float act = (g == 2) ? (2.f * sg - 1.f) : sg;

        float f  = __shfl(act, lw,      64);
        float ii = __shfl(act, 16 + lw, 64);
        float gg = __shfl(act, 32 + lw, 64);
        float oo = __shfl(act, 48 + lw, 64);

        cst = f * cst + ii * gg;
        float tn = 2.f / (1.f + __expf(-2.f * cst)) - 1.f;
        float hme = oo * tn;

        h0 = __shfl(hme, base4 | 0, 64);
        h1 = __shfl(hme, base4 | 1, 64);
        h2 = __shfl(hme, base4 | 2, 64);
        h3 = __shfl(hme, base4 | 3, 64);

        if (l < 4) outs[(size_t)(s * BATCH + b) * 4 + l] = hme;
    }
}

// ---------------------------------------------------------------------------
// logits + log_softmax: wave per (s,b) row, lane = tag.
// ---------------------------------------------------------------------------
__global__ __launch_bounds__(256) void logits_kernel(const float* __restrict__ outs,
                                                     const float* __restrict__ tag_w,
                                                     const float* __restrict__ tag_b,
                                                     float* __restrict__ out) {
    int l = threadIdx.x & 63;
    int wid = (blockIdx.x * blockDim.x + threadIdx.x) >> 6;
    int nw  = (gridDim.x * blockDim.x) >> 6;

    float4 w = *(const float4*)(tag_w + l * 4);
    float bb = tag_b[l];

    for (int row = wid; row < ROWS; row += nw) {
        float4 h = *(const float4*)(outs + (size_t)row * 4);
        float z = fmaf(h.x, w.x, fmaf(h.y, w.y, fmaf(h.z, w.z, fmaf(h.w, w.w, bb))));
        float m = z;
#pragma unroll
        for (int d = 1; d < 64; d <<= 1) m = fmaxf(m, __shfl_xor(m, d, 64));
        float e = __expf(z - m);
        float ssum = e;
#pragma unroll
        for (int d = 1; d < 64; d <<= 1) ssum += __shfl_xor(ssum, d, 64);
        out[(size_t)row * 64 + l] = (z - m) - __logf(ssum);
    }
}

// ---------------------------------------------------------------------------
extern "C" void kernel_launch(void* const* d_in, const int* in_sizes, int n_in,
                              void* d_out, int out_size, void* d_ws, size_t ws_size,
                              hipStream_t stream) {
    const int*   sent  = (const int*)d_in[0];
    const float* emb   = (const float*)d_in[1];
    const float* lin_w = (const float*)d_in[2];
    const float* lin_b = (const float*)d_in[3];
    const float* qrx   = (const float*)d_in[4];
    const float* qry   = (const float*)d_in[5];
    const float* qrz   = (const float*)d_in[6];
    const float* qcrx  = (const float*)d_in[7];
    const float* tag_w = (const float*)d_in[8];
    const float* tag_b = (const float*)d_in[9];
    float* out = (float*)d_out;

    char* ws = (char*)d_ws;
    float2* M    = (float2*)ws;                                   // 4*16*16*8 = 8 KB
    float*  angx = (float*)(ws + 8192);                           // ROWS*16*4 = 8 MB
    float*  outs = (float*)(ws + 8192 + (size_t)ROWS * 16 * 4);   // ROWS*4*4  = 2 MB

    setup_kernel<<<dim3(1), dim3(256), 0, stream>>>(qrx, qry, qrz, qcrx, M);
    angx_kernel<<<dim3(1024), dim3(256), 0, stream>>>(sent, emb, lin_w, lin_b, angx);
    lstm_kernel<<<dim3(128), dim3(256), 0, stream>>>(lin_w, M, angx, outs);
    logits_kernel<<<dim3(1024), dim3(256), 0, stream>>>(outs, tag_w, tag_b, out);
}

// Round 4
// 339.048 us; speedup vs baseline: 1.8309x; 1.1277x over previous
//
#include <hip/hip_runtime.h>
#include <math.h>

#define S_LEN 256
#define BATCH 512
#define ROWS (S_LEN * BATCH)

// ---------------------------------------------------------------------------
// Compile-time reproduction of np.random.RandomState(seed) op streams.
// ---------------------------------------------------------------------------
struct MTState {
    unsigned mt[624];
    int idx;
    constexpr MTState(unsigned seed) : mt{}, idx(624) {
        mt[0] = seed;
        for (int i = 1; i < 624; ++i)
            mt[i] = 1812433253u * (mt[i - 1] ^ (mt[i - 1] >> 30)) + (unsigned)i;
    }
    constexpr unsigned next() {
        if (idx >= 624) {
            for (int i = 0; i < 624; ++i) {
                unsigned y = (mt[i] & 0x80000000u) | (mt[(i + 1) % 624] & 0x7fffffffu);
                mt[i] = mt[(i + 397) % 624] ^ (y >> 1) ^ ((y & 1u) ? 2567483615u : 0u);
            }
            idx = 0;
        }
        unsigned y = mt[idx++];
        y ^= y >> 11;
        y ^= (y << 7)  & 2636928640u;
        y ^= (y << 15) & 4022730752u;
        y ^= y >> 18;
        return y;
    }
};

struct OpsTab {
    int   k [4][20];
    int   w0[4][20];
    int   w1[4][20];
    float t [4][20];
};

constexpr OpsTab make_ops() {
    OpsTab o{};
    for (int seed = 0; seed < 4; ++seed) {
        MTState rng((unsigned)seed);
        for (int i = 0; i < 20; ++i) {
            unsigned k = rng.next() & 3u;            // randint(4)
            if (k < 3u) {
                int w = (int)(rng.next() & 3u);      // randint(4)
                unsigned A = rng.next(), B = rng.next();  // rk_double
                double d = ((double)(A >> 5) * 67108864.0 + (double)(B >> 6))
                           / 9007199254740992.0;
                o.k[seed][i]  = (int)k;
                o.w0[seed][i] = w;
                o.w1[seed][i] = 0;
                o.t[seed][i]  = (float)(6.283185307179586 * d);
            } else {
                int w0 = (int)(rng.next() & 3u);     // randint(4)
                unsigned v = rng.next() & 3u;        // randint(3): reject >2
                while (v > 2u) v = rng.next() & 3u;
                o.k[seed][i]  = 3;
                o.w0[seed][i] = w0;
                o.w1[seed][i] = (int)((w0 + 1 + (int)v) & 3);
                o.t[seed][i]  = 0.f;
            }
        }
    }
    return o;
}

constexpr OpsTab OPS_CE = make_ops();

// ---------------------------------------------------------------------------
// Fully-unrolled circuit fold (all indices compile-time -> registers).
// Wire w <-> bit (3-w) of the flat state index.
// ---------------------------------------------------------------------------
template <int M>
__device__ inline void gate1(float (&sr)[16], float (&si)[16],
                             float g00r, float g00i, float g01r, float g01i,
                             float g10r, float g10i, float g11r, float g11i) {
#pragma unroll
    for (int r = 0; r < 16; ++r) {
        if (r & M) continue;
        const int r1 = r | M;
        float ar = sr[r], ai = si[r], br = sr[r1], bi = si[r1];
        sr[r]  = g00r * ar - g00i * ai + g01r * br - g01i * bi;
        si[r]  = g00r * ai + g00i * ar + g01r * bi + g01i * br;
        sr[r1] = g10r * ar - g10i * ai + g11r * br - g11i * bi;
        si[r1] = g10r * ai + g10i * ar + g11r * bi + g11i * br;
    }
}

template <int G, int O>
__device__ inline void apply_rand_ops(float (&sr)[16], float (&si)[16]) {
    if constexpr (O < 20) {
        constexpr int   k = OPS_CE.k[G][O];
        constexpr int   w = OPS_CE.w0[G][O];
        constexpr float t = OPS_CE.t[G][O];
        constexpr int   M = 8 >> w;
        if constexpr (k == 3) {
            constexpr int M1 = 8 >> OPS_CE.w1[G][O];
#pragma unroll
            for (int r = 0; r < 16; ++r) {
                if ((r & M) && !(r & M1)) {
                    const int r1 = r | M1;
                    float tr = sr[r]; sr[r] = sr[r1]; sr[r1] = tr;
                    tr = si[r]; si[r] = si[r1]; si[r1] = tr;
                }
            }
        } else {
            float c = cosf(0.5f * t), s = sinf(0.5f * t);
            if constexpr (k == 0)
                gate1<M>(sr, si, c, 0.f, 0.f, -s, 0.f, -s, c, 0.f);     // RX
            else if constexpr (k == 1)
                gate1<M>(sr, si, c, 0.f, -s, 0.f, s, 0.f, c, 0.f);      // RY
            else
                gate1<M>(sr, si, c, -s, 0.f, 0.f, 0.f, 0.f, c, s);      // RZ
        }
        apply_rand_ops<G, O + 1>(sr, si);
    }
}

template <int G, int W>
__device__ inline void ring_step(float (&sr)[16], float (&si)[16],
                                 const float* qrx, const float* qry,
                                 const float* qrz, const float* qcrx) {
    constexpr int M  = 8 >> W;
    constexpr int M1 = 8 >> ((W + 1) & 3);
    float t, c, s;
    t = qrx[G * 4 + W]; c = cosf(0.5f * t); s = sinf(0.5f * t);
    gate1<M>(sr, si, c, 0.f, 0.f, -s, 0.f, -s, c, 0.f);
    t = qry[G * 4 + W]; c = cosf(0.5f * t); s = sinf(0.5f * t);
    gate1<M>(sr, si, c, 0.f, -s, 0.f, s, 0.f, c, 0.f);
    t = qrz[G * 4 + W]; c = cosf(0.5f * t); s = sinf(0.5f * t);
    gate1<M>(sr, si, c, -s, 0.f, 0.f, 0.f, 0.f, c, s);
    t = qcrx[G * 4 + W]; c = cosf(0.5f * t); s = sinf(0.5f * t);
#pragma unroll
    for (int r = 0; r < 16; ++r) {
        if ((r & M) && !(r & M1)) {
            const int r1 = r | M1;
            float ar = sr[r], ai = si[r], br = sr[r1], bi = si[r1];
            sr[r]  = c * ar + s * bi;  si[r]  = c * ai - s * br;
            sr[r1] = c * br + s * ai;  si[r1] = c * bi - s * ar;
        }
    }
    if constexpr (W < 3) ring_step<G, W + 1>(sr, si, qrx, qry, qrz, qcrx);
}

template <int G>
__device__ inline void fold_circuit(int col, const float* qrx, const float* qry,
                                    const float* qrz, const float* qcrx,
                                    float* Mr, float* Mi, bool writer) {
    float sr[16], si[16];
#pragma unroll
    for (int r = 0; r < 16; ++r) { sr[r] = (r == col) ? 1.f : 0.f; si[r] = 0.f; }
    apply_rand_ops<G, 0>(sr, si);
    ring_step<G, 0>(sr, si, qrx, qry, qrz, qcrx);
    if (writer) {
#pragma unroll
        for (int r = 0; r < 16; ++r) {
            Mr[G * 256 + r * 16 + col] = sr[r];
            Mi[G * 256 + r * 16 + col] = si[r];
        }
    }
}

// factor for product-to-sum expansion: enc_j*enc_k per wire.
// t: 0->const, 1->cos, 2->sin basis.  bj,bk: wire bits of j,k.
__device__ inline float pfac(int t, int bj, int bk) {
    if (bj == bk)
        return (t == 0) ? 0.5f : (t == 1) ? (bj ? -0.5f : 0.5f) : 0.f;
    return (t == 2) ? 0.5f : 0.f;
}

// ---------------------------------------------------------------------------
// Setup: fold circuits -> M (LDS) -> Q = Re(M^T D_w M) (LDS) -> T tensor
// (16 (g,w) pairs x 81 coefficients over basis {1,cos a,sin a}^4) -> global.
// ---------------------------------------------------------------------------
__global__ __launch_bounds__(256) void setup_kernel(const float* __restrict__ qrx,
                                                    const float* __restrict__ qry,
                                                    const float* __restrict__ qrz,
                                                    const float* __restrict__ qcrx,
                                                    float* __restrict__ Tg) {
    __shared__ float Mr[4 * 256];
    __shared__ float Mi[4 * 256];
    __shared__ float Q[16 * 256];

    int tid = threadIdx.x;
    int g   = tid >> 6;
    int col = tid & 15;
    bool wr = (tid & 48) == 0;

    switch (g) {
        case 0: fold_circuit<0>(col, qrx, qry, qrz, qcrx, Mr, Mi, wr); break;
        case 1: fold_circuit<1>(col, qrx, qry, qrz, qcrx, Mr, Mi, wr); break;
        case 2: fold_circuit<2>(col, qrx, qry, qrz, qcrx, Mr, Mi, wr); break;
        case 3: fold_circuit<3>(col, qrx, qry, qrz, qcrx, Mr, Mi, wr); break;
    }
    __syncthreads();

    // Q[gw][j][k] = sum_r sigma_w(r) * (Mr[g][r][j]Mr[g][r][k] + Mi..Mi)
    for (int n = 0; n < 16; ++n) {
        int i  = tid * 16 + n;
        int gw = i >> 8, j = (i >> 4) & 15, k = i & 15;
        int gg2 = gw >> 2, w = gw & 3;
        float acc = 0.f;
        for (int r = 0; r < 16; ++r) {
            float sgn = ((r >> (3 - w)) & 1) ? -1.f : 1.f;
            float mrj = Mr[gg2 * 256 + r * 16 + j], mrk = Mr[gg2 * 256 + r * 16 + k];
            float mij = Mi[gg2 * 256 + r * 16 + j], mik = Mi[gg2 * 256 + r * 16 + k];
            acc += sgn * (mrj * mrk + mij * mik);
        }
        Q[gw * 256 + j * 16 + k] = acc;
    }
    __syncthreads();

    // T[gw][t0][t1][t2][t3] = sum_{j,k} Q[gw][j][k] * prod_w pfac(tw, bjw, bkw)
    if (tid < 144) {
        int gw = tid / 9, rem = tid % 9, t0 = rem / 3, t1 = rem % 3;
        float acc[3][3] = {};
        for (int jk = 0; jk < 256; ++jk) {
            int j = jk >> 4, k = jk & 15;
            int bj0 = (j >> 3) & 1, bk0 = (k >> 3) & 1;
            int bj1 = (j >> 2) & 1, bk1 = (k >> 2) & 1;
            int bj2 = (j >> 1) & 1, bk2 = (k >> 1) & 1;
            int bj3 = j & 1,        bk3 = k & 1;
            float f01 = pfac(t0, bj0, bk0) * pfac(t1, bj1, bk1);
            float base = Q[gw * 256 + jk] * f01;
#pragma unroll
            for (int t2 = 0; t2 < 3; ++t2) {
                float f2 = pfac(t2, bj2, bk2);
#pragma unroll
                for (int t3 = 0; t3 < 3; ++t3) {
                    float f3 = pfac(t3, bj3, bk3);
                    acc[t2][t3] = fmaf(base, f2 * f3, acc[t2][t3]);
                }
            }
        }
#pragma unroll
        for (int t2 = 0; t2 < 3; ++t2)
#pragma unroll
            for (int t3 = 0; t3 < 3; ++t3)
                Tg[gw * 81 + t0 * 27 + t1 * 9 + t2 * 3 + t3] = acc[t2][t3];
    }
}

// ---------------------------------------------------------------------------
// angx kernel: angx[row][g*4+q] = emb[tok[row]] . lin_w[g,q,:256] + lin_b
// ---------------------------------------------------------------------------
__global__ __launch_bounds__(256) void angx_kernel(const int* __restrict__ sent,
                                                   const float* __restrict__ emb,
                                                   const float* __restrict__ lin_w,
                                                   const float* __restrict__ lin_b,
                                                   float* __restrict__ angx) {
    int l  = threadIdx.x & 63;
    int q  = l & 15;
    int ch = l >> 4;
    int wid = (blockIdx.x * blockDim.x + threadIdx.x) >> 6;
    int nw  = (gridDim.x * blockDim.x) >> 6;

    const float* wr = lin_w + q * 260 + ch * 64;
    float w0[16], w1[16], w2[16], w3[16];
#pragma unroll
    for (int j = 0; j < 16; ++j) {
        float4 t = *(const float4*)(wr + j * 4);
        w0[j] = t.x; w1[j] = t.y; w2[j] = t.z; w3[j] = t.w;
    }
    float bias = lin_b[q];

    for (int row = wid; row < ROWS; row += nw) {
        int tok = sent[row];
        const float* er = emb + (size_t)tok * 256 + ch * 64;
        float acc = 0.f;
#pragma unroll
        for (int j = 0; j < 16; ++j) {
            float4 x = *(const float4*)(er + j * 4);
            acc = fmaf(x.x, w0[j], acc);
            acc = fmaf(x.y, w1[j], acc);
            acc = fmaf(x.z, w2[j], acc);
            acc = fmaf(x.w, w3[j], acc);
        }
        acc += __shfl_xor(acc, 16, 64);
        acc += __shfl_xor(acc, 32, 64);
        if (l < 16) angx[(size_t)row * 16 + q] = acc + bias;
    }
}

// ---------------------------------------------------------------------------
// Recurrence: lane l = (q<<4)|(w<<2)|g — 4 chains/wave, lane owns Z^{g,w}
// via the 81-term polynomial.  Cross-lane per step: 4 DPP quad broadcasts
// (act gather over g) + 4 ds_swizzle (h broadcast over w).  1-step prefetch.
// ---------------------------------------------------------------------------
__global__ __launch_bounds__(64) void lstm_kernel(const float* __restrict__ lin_w,
                                                  const float* __restrict__ Tg,
                                                  const float* __restrict__ angx,
                                                  float* __restrict__ outs) {
    int l = threadIdx.x;
    int g = l & 3;
    int w = (l >> 2) & 3;
    int q = l >> 4;
    int b = blockIdx.x * 4 + q;

    float T[81];
#pragma unroll
    for (int i = 0; i < 81; ++i) T[i] = Tg[(g * 4 + w) * 81 + i];

    float whh[4][4];
#pragma unroll
    for (int qq = 0; qq < 4; ++qq)
#pragma unroll
        for (int ww = 0; ww < 4; ++ww)
            whh[qq][ww] = lin_w[(g * 4 + qq) * 260 + 256 + ww];

    const float kk = (g == 2) ? 2.f : 1.f;
    const float sc = (g == 2) ? 2.f : 1.f;
    const float of = (g == 2) ? 1.f : 0.f;

    float h0 = 0.f, h1 = 0.f, h2 = 0.f, h3 = 0.f, cst = 0.f;

    float4 ax = *(const float4*)(angx + (size_t)b * 16 + g * 4);
    for (int s = 0; s < S_LEN; ++s) {
        int sn = (s + 1) & 255;
        float4 axn = *(const float4*)(angx + (size_t)(sn * BATCH + b) * 16 + g * 4);

        float a0 = fmaf(whh[0][3], h3, fmaf(whh[0][2], h2, fmaf(whh[0][1], h1, fmaf(whh[0][0], h0, ax.x))));
        float a1 = fmaf(whh[1][3], h3, fmaf(whh[1][2], h2, fmaf(whh[1][1], h1, fmaf(whh[1][0], h0, ax.y))));
        float a2 = fmaf(whh[2][3], h3, fmaf(whh[2][2], h2, fmaf(whh[2][1], h1, fmaf(whh[2][0], h0, ax.z))));
        float a3 = fmaf(whh[3][3], h3, fmaf(whh[3][2], h2, fmaf(whh[3][1], h1, fmaf(whh[3][0], h0, ax.w))));

        float c0 = __cosf(a0), s0 = __sinf(a0);
        float c1 = __cosf(a1), s1 = __sinf(a1);
        float c2 = __cosf(a2), s2 = __sinf(a2);
        float c3 = __cosf(a3), s3 = __sinf(a3);

        float yA[27];
#pragma unroll
        for (int i = 0; i < 27; ++i)
            yA[i] = fmaf(s3, T[i * 3 + 2], fmaf(c3, T[i * 3 + 1], T[i * 3]));
        float yB[9];
#pragma unroll
        for (int i = 0; i < 9; ++i)
            yB[i] = fmaf(s2, yA[i * 3 + 2], fmaf(c2, yA[i * 3 + 1], yA[i * 3]));
        float yC[3];
#pragma unroll
        for (int i = 0; i < 3; ++i)
            yC[i] = fmaf(s1, yB[i * 3 + 2], fmaf(c1, yB[i * 3 + 1], yB[i * 3]));
        float Z = fmaf(s0, yC[2], fmaf(c0, yC[1], yC[0]));

        float sg  = 1.f / (1.f + __expf(-kk * Z));
        float act = sc * sg - of;

        int ai = __float_as_int(act);
        float f  = __int_as_float(__builtin_amdgcn_update_dpp(0, ai, 0x00, 0xf, 0xf, true));
        float ii = __int_as_float(__builtin_amdgcn_update_dpp(0, ai, 0x55, 0xf, 0xf, true));
        float gg = __int_as_float(__builtin_amdgcn_update_dpp(0, ai, 0xAA, 0xf, 0xf, true));
        float oo = __int_as_float(__builtin_amdgcn_update_dpp(0, ai, 0xFF, 0xf, 0xf, true));

        cst = fmaf(f, cst, ii * gg);
        float tn = 2.f / (1.f + __expf(-2.f * cst)) - 1.f;
        float hme = oo * tn;

        if (g == 0) outs[(size_t)(s * BATCH + b) * 4 + w] = hme;

        int hi = __float_as_int(hme);
        h0 = __int_as_float(__builtin_amdgcn_ds_swizzle(hi, 0x013));
        h1 = __int_as_float(__builtin_amdgcn_ds_swizzle(hi, 0x093));
        h2 = __int_as_float(__builtin_amdgcn_ds_swizzle(hi, 0x113));
        h3 = __int_as_float(__builtin_amdgcn_ds_swizzle(hi, 0x193));

        ax = axn;
    }
}

// ---------------------------------------------------------------------------
// logits + log_softmax: wave per (s,b) row, lane = tag.
// ---------------------------------------------------------------------------
__global__ __launch_bounds__(256) void logits_kernel(const float* __restrict__ outs,
                                                     const float* __restrict__ tag_w,
                                                     const float* __restrict__ tag_b,
                                                     float* __restrict__ out) {
    int l = threadIdx.x & 63;
    int wid = (blockIdx.x * blockDim.x + threadIdx.x) >> 6;
    int nw  = (gridDim.x * blockDim.x) >> 6;

    float4 w = *(const float4*)(tag_w + l * 4);
    float bb = tag_b[l];

    for (int row = wid; row < ROWS; row += nw) {
        float4 h = *(const float4*)(outs + (size_t)row * 4);
        float z = fmaf(h.x, w.x, fmaf(h.y, w.y, fmaf(h.z, w.z, fmaf(h.w, w.w, bb))));
        float m = z;
#pragma unroll
        for (int d = 1; d < 64; d <<= 1) m = fmaxf(m, __shfl_xor(m, d, 64));
        float e = __expf(z - m);
        float ssum = e;
#pragma unroll
        for (int d = 1; d < 64; d <<= 1) ssum += __shfl_xor(ssum, d, 64);
        out[(size_t)row * 64 + l] = (z - m) - __logf(ssum);
    }
}

// ---------------------------------------------------------------------------
extern "C" void kernel_launch(void* const* d_in, const int* in_sizes, int n_in,
                              void* d_out, int out_size, void* d_ws, size_t ws_size,
                              hipStream_t stream) {
    const int*   sent  = (const int*)d_in[0];
    const float* emb   = (const float*)d_in[1];
    const float* lin_w = (const float*)d_in[2];
    const float* lin_b = (const float*)d_in[3];
    const float* qrx   = (const float*)d_in[4];
    const float* qry   = (const float*)d_in[5];
    const float* qrz   = (const float*)d_in[6];
    const float* qcrx  = (const float*)d_in[7];
    const float* tag_w = (const float*)d_in[8];
    const float* tag_b = (const float*)d_in[9];
    float* out = (float*)d_out;

    char* ws = (char*)d_ws;
    float*  Tg   = (float*)ws;                                    // 16*81*4 = 5184 B
    float*  angx = (float*)(ws + 8192);                           // ROWS*16*4 = 8 MB
    float*  outs = (float*)(ws + 8192 + (size_t)ROWS * 16 * 4);   // ROWS*4*4  = 2 MB

    setup_kernel<<<dim3(1), dim3(256), 0, stream>>>(qrx, qry, qrz, qcrx, Tg);
    angx_kernel<<<dim3(1024), dim3(256), 0, stream>>>(sent, emb, lin_w, lin_b, angx);
    lstm_kernel<<<dim3(128), dim3(64), 0, stream>>>(lin_w, Tg, angx, outs);
    logits_kernel<<<dim3(1024), dim3(256), 0, stream>>>(outs, tag_w, tag_b, out);
}

// Round 5
// 280.976 us; speedup vs baseline: 2.2093x; 1.2067x over previous
//
#include <hip/hip_runtime.h>
#include <math.h>

#define S_LEN 256
#define BATCH 512
#define ROWS (S_LEN * BATCH)

// ---------------------------------------------------------------------------
// Compile-time reproduction of np.random.RandomState(seed) op streams.
// ---------------------------------------------------------------------------
struct MTState {
    unsigned mt[624];
    int idx;
    constexpr MTState(unsigned seed) : mt{}, idx(624) {
        mt[0] = seed;
        for (int i = 1; i < 624; ++i)
            mt[i] = 1812433253u * (mt[i - 1] ^ (mt[i - 1] >> 30)) + (unsigned)i;
    }
    constexpr unsigned next() {
        if (idx >= 624) {
            for (int i = 0; i < 624; ++i) {
                unsigned y = (mt[i] & 0x80000000u) | (mt[(i + 1) % 624] & 0x7fffffffu);
                mt[i] = mt[(i + 397) % 624] ^ (y >> 1) ^ ((y & 1u) ? 2567483615u : 0u);
            }
            idx = 0;
        }
        unsigned y = mt[idx++];
        y ^= y >> 11;
        y ^= (y << 7)  & 2636928640u;
        y ^= (y << 15) & 4022730752u;
        y ^= y >> 18;
        return y;
    }
};

struct OpsTab {
    int   k [4][20];
    int   w0[4][20];
    int   w1[4][20];
    float t [4][20];
};

constexpr OpsTab make_ops() {
    OpsTab o{};
    for (int seed = 0; seed < 4; ++seed) {
        MTState rng((unsigned)seed);
        for (int i = 0; i < 20; ++i) {
            unsigned k = rng.next() & 3u;            // randint(4)
            if (k < 3u) {
                int w = (int)(rng.next() & 3u);      // randint(4)
                unsigned A = rng.next(), B = rng.next();  // rk_double
                double d = ((double)(A >> 5) * 67108864.0 + (double)(B >> 6))
                           / 9007199254740992.0;
                o.k[seed][i]  = (int)k;
                o.w0[seed][i] = w;
                o.w1[seed][i] = 0;
                o.t[seed][i]  = (float)(6.283185307179586 * d);
            } else {
                int w0 = (int)(rng.next() & 3u);     // randint(4)
                unsigned v = rng.next() & 3u;        // randint(3): reject >2
                while (v > 2u) v = rng.next() & 3u;
                o.k[seed][i]  = 3;
                o.w0[seed][i] = w0;
                o.w1[seed][i] = (int)((w0 + 1 + (int)v) & 3);
                o.t[seed][i]  = 0.f;
            }
        }
    }
    return o;
}

__constant__ OpsTab OPS = make_ops();

// factor for product-to-sum expansion: enc_j*enc_k per wire.
// t: 0->const, 1->cos, 2->sin basis.  bj,bk: wire bits of j,k.
__device__ inline float pfac(int t, int bj, int bk) {
    if (bj == bk)
        return (t == 0) ? 0.5f : (t == 1) ? (bj ? -0.5f : 0.5f) : 0.f;
    return (t == 2) ? 0.5f : 0.f;
}

// ---------------------------------------------------------------------------
// Setup: lane-parallel circuit fold (one amplitude per lane; gates = shfl to
// partner + ~10 VALU in a small runtime loop -> ~3KB code, no icache storm).
// 1024 threads: wave wv -> g = wv>>2, column block = (wv&3); lane l -> state
// index r = l&15, column = (wv&3)*4 + (l>>4).
// Then Q = Re(M^T D_w M), then T tensor (16 pairs x 81 coeffs) -> global.
// Wire w <-> bit (3-w) of the state index.
// ---------------------------------------------------------------------------
__global__ __launch_bounds__(1024) void setup_kernel(const float* __restrict__ qrx,
                                                     const float* __restrict__ qry,
                                                     const float* __restrict__ qrz,
                                                     const float* __restrict__ qcrx,
                                                     float* __restrict__ Tg) {
    __shared__ float Mr[4 * 256];
    __shared__ float Mi[4 * 256];
    __shared__ float Q[16 * 256];

    int tid = threadIdx.x;
    int wv  = tid >> 6;
    int l   = tid & 63;
    int g   = wv >> 2;
    int r   = l & 15;
    int col = (wv & 3) * 4 + (l >> 4);

    float ar = (r == col) ? 1.f : 0.f;
    float ai = 0.f;
    int lbase = l & 48;

    // --- random layer (runtime loop, wave-uniform branches on k) ---
    for (int o = 0; o < 20; ++o) {
        int   k  = OPS.k[g][o];
        int   w  = OPS.w0[g][o];
        float th = OPS.t[g][o];
        if (k == 3) {
            int M1  = 8 >> OPS.w1[g][o];
            int M0  = 8 >> w;
            int src = lbase | (r ^ M1);
            float br = __shfl(ar, src, 64);
            float bi = __shfl(ai, src, 64);
            bool ctrl = (r & M0) != 0;
            ar = ctrl ? br : ar;
            ai = ctrl ? bi : ai;
        } else {
            int M = 8 >> w;
            float c = cosf(0.5f * th), s = sinf(0.5f * th);
            bool hi = (r & M) != 0;
            float Ar = c, Ai = 0.f, Br = 0.f, Bi = 0.f;
            if (k == 0) { Bi = -s; }                       // RX
            else if (k == 1) { Br = hi ? s : -s; }         // RY
            else { Ai = hi ? s : -s; }                     // RZ
            int src = lbase | (r ^ M);
            float br = __shfl(ar, src, 64);
            float bi = __shfl(ai, src, 64);
            float nr = Ar * ar - Ai * ai + Br * br - Bi * bi;
            float ni = Ar * ai + Ai * ar + Br * bi + Bi * br;
            ar = nr; ai = ni;
        }
    }

    // --- trainable ring (runtime loop over wires) ---
    for (int w = 0; w < 4; ++w) {
        int M  = 8 >> w;
        int M1 = 8 >> ((w + 1) & 3);
        bool hi = (r & M) != 0;
        int src = lbase | (r ^ M);
        float th, c, s, br, bi, nr, ni;

        th = qrx[g * 4 + w]; c = cosf(0.5f * th); s = sinf(0.5f * th);
        br = __shfl(ar, src, 64); bi = __shfl(ai, src, 64);
        nr = c * ar + s * bi;  ni = c * ai - s * br;       // RX: B = -i s
        ar = nr; ai = ni;

        th = qry[g * 4 + w]; c = cosf(0.5f * th); s = sinf(0.5f * th);
        br = __shfl(ar, src, 64); bi = __shfl(ai, src, 64);
        { float B = hi ? s : -s;
          nr = c * ar + B * br;  ni = c * ai + B * bi; }   // RY
        ar = nr; ai = ni;

        th = qrz[g * 4 + w]; c = cosf(0.5f * th); s = sinf(0.5f * th);
        { float Ai2 = hi ? s : -s;
          nr = c * ar - Ai2 * ai;  ni = c * ai + Ai2 * ar; } // RZ
        ar = nr; ai = ni;

        th = qcrx[g * 4 + w]; c = cosf(0.5f * th); s = sinf(0.5f * th);
        int src1 = lbase | (r ^ M1);
        br = __shfl(ar, src1, 64); bi = __shfl(ai, src1, 64);
        bool ctrl = hi;
        nr = c * ar + s * bi;  ni = c * ai - s * br;       // CRX on target
        ar = ctrl ? nr : ar;
        ai = ctrl ? ni : ai;
    }

    Mr[g * 256 + r * 16 + col] = ar;
    Mi[g * 256 + r * 16 + col] = ai;
    __syncthreads();

    // Q[gw][j][k] = sum_r sigma_w(r) * (Mr[g][r][j]Mr[g][r][k] + Mi..Mi)
    for (int n = 0; n < 4; ++n) {
        int i  = tid * 4 + n;
        int gw = i >> 8, j = (i >> 4) & 15, kk = i & 15;
        int gg2 = gw >> 2, w = gw & 3;
        float acc = 0.f;
        for (int rr = 0; rr < 16; ++rr) {
            float sgn = ((rr >> (3 - w)) & 1) ? -1.f : 1.f;
            float mrj = Mr[gg2 * 256 + rr * 16 + j], mrk = Mr[gg2 * 256 + rr * 16 + kk];
            float mij = Mi[gg2 * 256 + rr * 16 + j], mik = Mi[gg2 * 256 + rr * 16 + kk];
            acc += sgn * (mrj * mrk + mij * mik);
        }
        Q[gw * 256 + j * 16 + kk] = acc;
    }
    __syncthreads();

    // T[gw][t0][t1][t2][t3] = sum_{j,k} Q[gw][j][k] * prod_w pfac(tw, bjw, bkw)
    if (tid < 144) {
        int gw = tid / 9, rem = tid % 9, t0 = rem / 3, t1 = rem % 3;
        float acc[3][3] = {};
        for (int jk = 0; jk < 256; ++jk) {
            int j = jk >> 4, kq = jk & 15;
            int bj0 = (j >> 3) & 1, bk0 = (kq >> 3) & 1;
            int bj1 = (j >> 2) & 1, bk1 = (kq >> 2) & 1;
            int bj2 = (j >> 1) & 1, bk2 = (kq >> 1) & 1;
            int bj3 = j & 1,        bk3 = kq & 1;
            float f01 = pfac(t0, bj0, bk0) * pfac(t1, bj1, bk1);
            float base = Q[gw * 256 + jk] * f01;
#pragma unroll
            for (int t2 = 0; t2 < 3; ++t2) {
                float f2 = pfac(t2, bj2, bk2);
#pragma unroll
                for (int t3 = 0; t3 < 3; ++t3) {
                    float f3 = pfac(t3, bj3, bk3);
                    acc[t2][t3] = fmaf(base, f2 * f3, acc[t2][t3]);
                }
            }
        }
#pragma unroll
        for (int t2 = 0; t2 < 3; ++t2)
#pragma unroll
            for (int t3 = 0; t3 < 3; ++t3)
                Tg[gw * 81 + t0 * 27 + t1 * 9 + t2 * 3 + t3] = acc[t2][t3];
    }
}

// ---------------------------------------------------------------------------
// angx kernel: angx[row][g*4+q] = emb[tok[row]] . lin_w[g,q,:256] + lin_b
// ---------------------------------------------------------------------------
__global__ __launch_bounds__(256) void angx_kernel(const int* __restrict__ sent,
                                                   const float* __restrict__ emb,
                                                   const float* __restrict__ lin_w,
                                                   const float* __restrict__ lin_b,
                                                   float* __restrict__ angx) {
    int l  = threadIdx.x & 63;
    int q  = l & 15;
    int ch = l >> 4;
    int wid = (blockIdx.x * blockDim.x + threadIdx.x) >> 6;
    int nw  = (gridDim.x * blockDim.x) >> 6;

    const float* wr = lin_w + q * 260 + ch * 64;
    float w0[16], w1[16], w2[16], w3[16];
#pragma unroll
    for (int j = 0; j < 16; ++j) {
        float4 t = *(const float4*)(wr + j * 4);
        w0[j] = t.x; w1[j] = t.y; w2[j] = t.z; w3[j] = t.w;
    }
    float bias = lin_b[q];

    for (int row = wid; row < ROWS; row += nw) {
        int tok = sent[row];
        const float* er = emb + (size_t)tok * 256 + ch * 64;
        float acc = 0.f;
#pragma unroll
        for (int j = 0; j < 16; ++j) {
            float4 x = *(const float4*)(er + j * 4);
            acc = fmaf(x.x, w0[j], acc);
            acc = fmaf(x.y, w1[j], acc);
            acc = fmaf(x.z, w2[j], acc);
            acc = fmaf(x.w, w3[j], acc);
        }
        acc += __shfl_xor(acc, 16, 64);
        acc += __shfl_xor(acc, 32, 64);
        if (l < 16) angx[(size_t)row * 16 + q] = acc + bias;
    }
}

// ---------------------------------------------------------------------------
// Recurrence: lane l = (q<<4)|(w<<2)|g — 4 chains/wave, lane owns Z^{g,w}
// via the 81-term polynomial.  Cross-lane per step: 4 DPP quad broadcasts
// (act gather over g) + 4 ds_swizzle (h broadcast over w).  1-step prefetch.
// ---------------------------------------------------------------------------
__global__ __launch_bounds__(64) void lstm_kernel(const float* __restrict__ lin_w,
                                                  const float* __restrict__ Tg,
                                                  const float* __restrict__ angx,
                                                  float* __restrict__ outs) {
    int l = threadIdx.x;
    int g = l & 3;
    int w = (l >> 2) & 3;
    int q = l >> 4;
    int b = blockIdx.x * 4 + q;

    float T[81];
#pragma unroll
    for (int i = 0; i < 81; ++i) T[i] = Tg[(g * 4 + w) * 81 + i];

    float whh[4][4];
#pragma unroll
    for (int qq = 0; qq < 4; ++qq)
#pragma unroll
        for (int ww = 0; ww < 4; ++ww)
            whh[qq][ww] = lin_w[(g * 4 + qq) * 260 + 256 + ww];

    const float kk = (g == 2) ? 2.f : 1.f;
    const float sc = (g == 2) ? 2.f : 1.f;
    const float of = (g == 2) ? 1.f : 0.f;

    float h0 = 0.f, h1 = 0.f, h2 = 0.f, h3 = 0.f, cst = 0.f;

    float4 ax = *(const float4*)(angx + (size_t)b * 16 + g * 4);
    for (int s = 0; s < S_LEN; ++s) {
        int sn = (s + 1) & 255;
        float4 axn = *(const float4*)(angx + (size_t)(sn * BATCH + b) * 16 + g * 4);

        float a0 = fmaf(whh[0][3], h3, fmaf(whh[0][2], h2, fmaf(whh[0][1], h1, fmaf(whh[0][0], h0, ax.x))));
        float a1 = fmaf(whh[1][3], h3, fmaf(whh[1][2], h2, fmaf(whh[1][1], h1, fmaf(whh[1][0], h0, ax.y))));
        float a2 = fmaf(whh[2][3], h3, fmaf(whh[2][2], h2, fmaf(whh[2][1], h1, fmaf(whh[2][0], h0, ax.z))));
        float a3 = fmaf(whh[3][3], h3, fmaf(whh[3][2], h2, fmaf(whh[3][1], h1, fmaf(whh[3][0], h0, ax.w))));

        float c0 = __cosf(a0), s0 = __sinf(a0);
        float c1 = __cosf(a1), s1 = __sinf(a1);
        float c2 = __cosf(a2), s2 = __sinf(a2);
        float c3 = __cosf(a3), s3 = __sinf(a3);

        float yA[27];
#pragma unroll
        for (int i = 0; i < 27; ++i)
            yA[i] = fmaf(s3, T[i * 3 + 2], fmaf(c3, T[i * 3 + 1], T[i * 3]));
        float yB[9];
#pragma unroll
        for (int i = 0; i < 9; ++i)
            yB[i] = fmaf(s2, yA[i * 3 + 2], fmaf(c2, yA[i * 3 + 1], yA[i * 3]));
        float yC[3];
#pragma unroll
        for (int i = 0; i < 3; ++i)
            yC[i] = fmaf(s1, yB[i * 3 + 2], fmaf(c1, yB[i * 3 + 1], yB[i * 3]));
        float Z = fmaf(s0, yC[2], fmaf(c0, yC[1], yC[0]));

        float sg  = 1.f / (1.f + __expf(-kk * Z));
        float act = sc * sg - of;

        int ai = __float_as_int(act);
        float f  = __int_as_float(__builtin_amdgcn_update_dpp(0, ai, 0x00, 0xf, 0xf, true));
        float ii = __int_as_float(__builtin_amdgcn_update_dpp(0, ai, 0x55, 0xf, 0xf, true));
        float gg = __int_as_float(__builtin_amdgcn_update_dpp(0, ai, 0xAA, 0xf, 0xf, true));
        float oo = __int_as_float(__builtin_amdgcn_update_dpp(0, ai, 0xFF, 0xf, 0xf, true));

        cst = fmaf(f, cst, ii * gg);
        float tn = 2.f / (1.f + __expf(-2.f * cst)) - 1.f;
        float hme = oo * tn;

        if (g == 0) outs[(size_t)(s * BATCH + b) * 4 + w] = hme;

        int hi = __float_as_int(hme);
        h0 = __int_as_float(__builtin_amdgcn_ds_swizzle(hi, 0x013));
        h1 = __int_as_float(__builtin_amdgcn_ds_swizzle(hi, 0x093));
        h2 = __int_as_float(__builtin_amdgcn_ds_swizzle(hi, 0x113));
        h3 = __int_as_float(__builtin_amdgcn_ds_swizzle(hi, 0x193));

        ax = axn;
    }
}

// ---------------------------------------------------------------------------
// logits + log_softmax: wave per (s,b) row, lane = tag.
// ---------------------------------------------------------------------------
__global__ __launch_bounds__(256) void logits_kernel(const float* __restrict__ outs,
                                                     const float* __restrict__ tag_w,
                                                     const float* __restrict__ tag_b,
                                                     float* __restrict__ out) {
    int l = threadIdx.x & 63;
    int wid = (blockIdx.x * blockDim.x + threadIdx.x) >> 6;
    int nw  = (gridDim.x * blockDim.x) >> 6;

    float4 w = *(const float4*)(tag_w + l * 4);
    float bb = tag_b[l];

    for (int row = wid; row < ROWS; row += nw) {
        float4 h = *(const float4*)(outs + (size_t)row * 4);
        float z = fmaf(h.x, w.x, fmaf(h.y, w.y, fmaf(h.z, w.z, fmaf(h.w, w.w, bb))));
        float m = z;
#pragma unroll
        for (int d = 1; d < 64; d <<= 1) m = fmaxf(m, __shfl_xor(m, d, 64));
        float e = __expf(z - m);
        float ssum = e;
#pragma unroll
        for (int d = 1; d < 64; d <<= 1) ssum += __shfl_xor(ssum, d, 64);
        out[(size_t)row * 64 + l] = (z - m) - __logf(ssum);
    }
}

// ---------------------------------------------------------------------------
extern "C" void kernel_launch(void* const* d_in, const int* in_sizes, int n_in,
                              void* d_out, int out_size, void* d_ws, size_t ws_size,
                              hipStream_t stream) {
    const int*   sent  = (const int*)d_in[0];
    const float* emb   = (const float*)d_in[1];
    const float* lin_w = (const float*)d_in[2];
    const float* lin_b = (const float*)d_in[3];
    const float* qrx   = (const float*)d_in[4];
    const float* qry   = (const float*)d_in[5];
    const float* qrz   = (const float*)d_in[6];
    const float* qcrx  = (const float*)d_in[7];
    const float* tag_w = (const float*)d_in[8];
    const float* tag_b = (const float*)d_in[9];
    float* out = (float*)d_out;

    char* ws = (char*)d_ws;
    float*  Tg   = (float*)ws;                                    // 16*81*4 = 5184 B
    float*  angx = (float*)(ws + 8192);                           // ROWS*16*4 = 8 MB
    float*  outs = (float*)(ws + 8192 + (size_t)ROWS * 16 * 4);   // ROWS*4*4  = 2 MB

    setup_kernel<<<dim3(1), dim3(1024), 0, stream>>>(qrx, qry, qrz, qcrx, Tg);
    angx_kernel<<<dim3(1024), dim3(256), 0, stream>>>(sent, emb, lin_w, lin_b, angx);
    lstm_kernel<<<dim3(128), dim3(64), 0, stream>>>(lin_w, Tg, angx, outs);
    logits_kernel<<<dim3(1024), dim3(256), 0, stream>>>(outs, tag_w, tag_b, out);
}

// Round 6
// 254.089 us; speedup vs baseline: 2.4431x; 1.1058x over previous
//
#include <hip/hip_runtime.h>
#include <math.h>

#define S_LEN 256
#define BATCH 512
#define ROWS (S_LEN * BATCH)

// ---------------------------------------------------------------------------
// Compile-time reproduction of np.random.RandomState(seed) op streams.
// ---------------------------------------------------------------------------
struct MTState {
    unsigned mt[624];
    int idx;
    constexpr MTState(unsigned seed) : mt{}, idx(624) {
        mt[0] = seed;
        for (int i = 1; i < 624; ++i)
            mt[i] = 1812433253u * (mt[i - 1] ^ (mt[i - 1] >> 30)) + (unsigned)i;
    }
    constexpr unsigned next() {
        if (idx >= 624) {
            for (int i = 0; i < 624; ++i) {
                unsigned y = (mt[i] & 0x80000000u) | (mt[(i + 1) % 624] & 0x7fffffffu);
                mt[i] = mt[(i + 397) % 624] ^ (y >> 1) ^ ((y & 1u) ? 2567483615u : 0u);
            }
            idx = 0;
        }
        unsigned y = mt[idx++];
        y ^= y >> 11;
        y ^= (y << 7)  & 2636928640u;
        y ^= (y << 15) & 4022730752u;
        y ^= y >> 18;
        return y;
    }
};

struct OpsTab {
    int   k [4][20];
    int   w0[4][20];
    int   w1[4][20];
    float t [4][20];
};

constexpr OpsTab make_ops() {
    OpsTab o{};
    for (int seed = 0; seed < 4; ++seed) {
        MTState rng((unsigned)seed);
        for (int i = 0; i < 20; ++i) {
            unsigned k = rng.next() & 3u;            // randint(4)
            if (k < 3u) {
                int w = (int)(rng.next() & 3u);      // randint(4)
                unsigned A = rng.next(), B = rng.next();  // rk_double
                double d = ((double)(A >> 5) * 67108864.0 + (double)(B >> 6))
                           / 9007199254740992.0;
                o.k[seed][i]  = (int)k;
                o.w0[seed][i] = w;
                o.w1[seed][i] = 0;
                o.t[seed][i]  = (float)(6.283185307179586 * d);
            } else {
                int w0 = (int)(rng.next() & 3u);     // randint(4)
                unsigned v = rng.next() & 3u;        // randint(3): reject >2
                while (v > 2u) v = rng.next() & 3u;
                o.k[seed][i]  = 3;
                o.w0[seed][i] = w0;
                o.w1[seed][i] = (int)((w0 + 1 + (int)v) & 3);
                o.t[seed][i]  = 0.f;
            }
        }
    }
    return o;
}

__constant__ OpsTab OPS = make_ops();

// factor for product-to-sum expansion: enc_j*enc_k per wire.
// t: 0->const, 1->cos, 2->sin basis.  bj,bk: wire bits of j,k.
__device__ inline float pfac(int t, int bj, int bk) {
    if (bj == bk)
        return (t == 0) ? 0.5f : (t == 1) ? (bj ? -0.5f : 0.5f) : 0.f;
    return (t == 2) ? 0.5f : 0.f;
}

// ---------------------------------------------------------------------------
// Setup: lane-parallel circuit fold (one amplitude per lane; gates = shfl to
// partner + ~10 VALU in a small runtime loop -> small code, no icache storm).
// Then Q = Re(M^T D_w M), then T tensor (16 pairs x 81 coeffs) -> global.
// Wire w <-> bit (3-w) of the state index.
// ---------------------------------------------------------------------------
__global__ __launch_bounds__(1024) void setup_kernel(const float* __restrict__ qrx,
                                                     const float* __restrict__ qry,
                                                     const float* __restrict__ qrz,
                                                     const float* __restrict__ qcrx,
                                                     float* __restrict__ Tg) {
    __shared__ float Mr[4 * 256];
    __shared__ float Mi[4 * 256];
    __shared__ float Q[16 * 256];

    int tid = threadIdx.x;
    int wv  = tid >> 6;
    int l   = tid & 63;
    int g   = wv >> 2;
    int r   = l & 15;
    int col = (wv & 3) * 4 + (l >> 4);

    float ar = (r == col) ? 1.f : 0.f;
    float ai = 0.f;
    int lbase = l & 48;

    // --- random layer (runtime loop, wave-uniform branches on k) ---
    for (int o = 0; o < 20; ++o) {
        int   k  = OPS.k[g][o];
        int   w  = OPS.w0[g][o];
        float th = OPS.t[g][o];
        if (k == 3) {
            int M1  = 8 >> OPS.w1[g][o];
            int M0  = 8 >> w;
            int src = lbase | (r ^ M1);
            float br = __shfl(ar, src, 64);
            float bi = __shfl(ai, src, 64);
            bool ctrl = (r & M0) != 0;
            ar = ctrl ? br : ar;
            ai = ctrl ? bi : ai;
        } else {
            int M = 8 >> w;
            float c = cosf(0.5f * th), s = sinf(0.5f * th);
            bool hi = (r & M) != 0;
            float Ar = c, Ai = 0.f, Br = 0.f, Bi = 0.f;
            if (k == 0) { Bi = -s; }                       // RX
            else if (k == 1) { Br = hi ? s : -s; }         // RY
            else { Ai = hi ? s : -s; }                     // RZ
            int src = lbase | (r ^ M);
            float br = __shfl(ar, src, 64);
            float bi = __shfl(ai, src, 64);
            float nr = Ar * ar - Ai * ai + Br * br - Bi * bi;
            float ni = Ar * ai + Ai * ar + Br * bi + Bi * br;
            ar = nr; ai = ni;
        }
    }

    // --- trainable ring (runtime loop over wires) ---
    for (int w = 0; w < 4; ++w) {
        int M  = 8 >> w;
        int M1 = 8 >> ((w + 1) & 3);
        bool hi = (r & M) != 0;
        int src = lbase | (r ^ M);
        float th, c, s, br, bi, nr, ni;

        th = qrx[g * 4 + w]; c = cosf(0.5f * th); s = sinf(0.5f * th);
        br = __shfl(ar, src, 64); bi = __shfl(ai, src, 64);
        nr = c * ar + s * bi;  ni = c * ai - s * br;       // RX: B = -i s
        ar = nr; ai = ni;

        th = qry[g * 4 + w]; c = cosf(0.5f * th); s = sinf(0.5f * th);
        br = __shfl(ar, src, 64); bi = __shfl(ai, src, 64);
        { float B = hi ? s : -s;
          nr = c * ar + B * br;  ni = c * ai + B * bi; }   // RY
        ar = nr; ai = ni;

        th = qrz[g * 4 + w]; c = cosf(0.5f * th); s = sinf(0.5f * th);
        { float Ai2 = hi ? s : -s;
          nr = c * ar - Ai2 * ai;  ni = c * ai + Ai2 * ar; } // RZ
        ar = nr; ai = ni;

        th = qcrx[g * 4 + w]; c = cosf(0.5f * th); s = sinf(0.5f * th);
        int src1 = lbase | (r ^ M1);
        br = __shfl(ar, src1, 64); bi = __shfl(ai, src1, 64);
        bool ctrl = hi;
        nr = c * ar + s * bi;  ni = c * ai - s * br;       // CRX on target
        ar = ctrl ? nr : ar;
        ai = ctrl ? ni : ai;
    }

    Mr[g * 256 + r * 16 + col] = ar;
    Mi[g * 256 + r * 16 + col] = ai;
    __syncthreads();

    // Q[gw][j][k] = sum_r sigma_w(r) * (Mr[g][r][j]Mr[g][r][k] + Mi..Mi)
    for (int n = 0; n < 4; ++n) {
        int i  = tid * 4 + n;
        int gw = i >> 8, j = (i >> 4) & 15, kk = i & 15;
        int gg2 = gw >> 2, w = gw & 3;
        float acc = 0.f;
        for (int rr = 0; rr < 16; ++rr) {
            float sgn = ((rr >> (3 - w)) & 1) ? -1.f : 1.f;
            float mrj = Mr[gg2 * 256 + rr * 16 + j], mrk = Mr[gg2 * 256 + rr * 16 + kk];
            float mij = Mi[gg2 * 256 + rr * 16 + j], mik = Mi[gg2 * 256 + rr * 16 + kk];
            acc += sgn * (mrj * mrk + mij * mik);
        }
        Q[gw * 256 + j * 16 + kk] = acc;
    }
    __syncthreads();

    // T[gw][t0][t1][t2][t3] = sum_{j,k} Q[gw][j][k] * prod_w pfac(tw, bjw, bkw)
    if (tid < 144) {
        int gw = tid / 9, rem = tid % 9, t0 = rem / 3, t1 = rem % 3;
        float acc[3][3] = {};
        for (int jk = 0; jk < 256; ++jk) {
            int j = jk >> 4, kq = jk & 15;
            int bj0 = (j >> 3) & 1, bk0 = (kq >> 3) & 1;
            int bj1 = (j >> 2) & 1, bk1 = (kq >> 2) & 1;
            int bj2 = (j >> 1) & 1, bk2 = (kq >> 1) & 1;
            int bj3 = j & 1,        bk3 = kq & 1;
            float f01 = pfac(t0, bj0, bk0) * pfac(t1, bj1, bk1);
            float base = Q[gw * 256 + jk] * f01;
#pragma unroll
            for (int t2 = 0; t2 < 3; ++t2) {
                float f2 = pfac(t2, bj2, bk2);
#pragma unroll
                for (int t3 = 0; t3 < 3; ++t3) {
                    float f3 = pfac(t3, bj3, bk3);
                    acc[t2][t3] = fmaf(base, f2 * f3, acc[t2][t3]);
                }
            }
        }
#pragma unroll
        for (int t2 = 0; t2 < 3; ++t2)
#pragma unroll
            for (int t3 = 0; t3 < 3; ++t3)
                Tg[gw * 81 + t0 * 27 + t1 * 9 + t2 * 3 + t3] = acc[t2][t3];
    }
}

// ---------------------------------------------------------------------------
// angx kernel: angx[row][g*4+q] = emb[tok[row]] . lin_w[g,q,:256] + lin_b
// ---------------------------------------------------------------------------
__global__ __launch_bounds__(256) void angx_kernel(const int* __restrict__ sent,
                                                   const float* __restrict__ emb,
                                                   const float* __restrict__ lin_w,
                                                   const float* __restrict__ lin_b,
                                                   float* __restrict__ angx) {
    int l  = threadIdx.x & 63;
    int q  = l & 15;
    int ch = l >> 4;
    int wid = (blockIdx.x * blockDim.x + threadIdx.x) >> 6;
    int nw  = (gridDim.x * blockDim.x) >> 6;

    const float* wr = lin_w + q * 260 + ch * 64;
    float w0[16], w1[16], w2[16], w3[16];
#pragma unroll
    for (int j = 0; j < 16; ++j) {
        float4 t = *(const float4*)(wr + j * 4);
        w0[j] = t.x; w1[j] = t.y; w2[j] = t.z; w3[j] = t.w;
    }
    float bias = lin_b[q];

    for (int row = wid; row < ROWS; row += nw) {
        int tok = sent[row];
        const float* er = emb + (size_t)tok * 256 + ch * 64;
        float acc = 0.f;
#pragma unroll
        for (int j = 0; j < 16; ++j) {
            float4 x = *(const float4*)(er + j * 4);
            acc = fmaf(x.x, w0[j], acc);
            acc = fmaf(x.y, w1[j], acc);
            acc = fmaf(x.z, w2[j], acc);
            acc = fmaf(x.w, w3[j], acc);
        }
        acc += __shfl_xor(acc, 16, 64);
        acc += __shfl_xor(acc, 32, 64);
        if (l < 16) angx[(size_t)row * 16 + q] = acc + bias;
    }
}

// ---------------------------------------------------------------------------
// Recurrence: lane l = (q<<4)|(w<<2)|g — 4 chains/wave, lane owns Z^{g,w}
// via the 81-term polynomial.  Cross-lane per step: 4 DPP quad broadcasts
// (act gather over g) + 3 DPP row_ror (h broadcast over w; weights permuted
// per-lane so rotation index aligns).  Depth-4 register prefetch of angx.
// ---------------------------------------------------------------------------
__global__ __launch_bounds__(64) void lstm_kernel(const float* __restrict__ lin_w,
                                                  const float* __restrict__ Tg,
                                                  const float* __restrict__ angx,
                                                  float* __restrict__ outs) {
    int l = threadIdx.x;
    int g = l & 3;
    int w = (l >> 2) & 3;
    int q = l >> 4;
    int b = blockIdx.x * 4 + q;

    float T[81];
#pragma unroll
    for (int i = 0; i < 81; ++i) T[i] = Tg[(g * 4 + w) * 81 + i];

    // whp[q][k] = whh[q][(w-k)&3] so that a_q = ax.q + sum_k whp[q][k]*hr_k
    // with hr_k = h_{(w-k)&3} delivered by DPP row_ror:4k.
    float whp[4][4];
#pragma unroll
    for (int qq = 0; qq < 4; ++qq)
#pragma unroll
        for (int k = 0; k < 4; ++k)
            whp[qq][k] = lin_w[(g * 4 + qq) * 260 + 256 + ((w - k) & 3)];

    const float kk = (g == 2) ? 2.f : 1.f;
    const float sc = (g == 2) ? 2.f : 1.f;
    const float of = (g == 2) ? 1.f : 0.f;

    float hr0 = 0.f, hr1 = 0.f, hr2 = 0.f, hr3 = 0.f, cst = 0.f;

    const float* ap = angx + (size_t)b * 16 + g * 4;   // step stride 8192 floats
    float* op = outs + (size_t)b * 4 + w;              // step stride 2048 floats

    float4 A0 = *(const float4*)(ap + 0 * 8192);
    float4 A1 = *(const float4*)(ap + 1 * 8192);
    float4 A2 = *(const float4*)(ap + 2 * 8192);
    float4 A3 = *(const float4*)(ap + 3 * 8192);

    auto step = [&](float4 ax, int sidx) {
        float a0 = fmaf(whp[0][3], hr3, fmaf(whp[0][2], hr2, fmaf(whp[0][1], hr1, fmaf(whp[0][0], hr0, ax.x))));
        float a1 = fmaf(whp[1][3], hr3, fmaf(whp[1][2], hr2, fmaf(whp[1][1], hr1, fmaf(whp[1][0], hr0, ax.y))));
        float a2 = fmaf(whp[2][3], hr3, fmaf(whp[2][2], hr2, fmaf(whp[2][1], hr1, fmaf(whp[2][0], hr0, ax.z))));
        float a3 = fmaf(whp[3][3], hr3, fmaf(whp[3][2], hr2, fmaf(whp[3][1], hr1, fmaf(whp[3][0], hr0, ax.w))));

        float c0 = __cosf(a0), s0 = __sinf(a0);
        float c1 = __cosf(a1), s1 = __sinf(a1);
        float c2 = __cosf(a2), s2 = __sinf(a2);
        float c3 = __cosf(a3), s3 = __sinf(a3);

        float yA[27];
#pragma unroll
        for (int i = 0; i < 27; ++i)
            yA[i] = fmaf(s3, T[i * 3 + 2], fmaf(c3, T[i * 3 + 1], T[i * 3]));
        float yB[9];
#pragma unroll
        for (int i = 0; i < 9; ++i)
            yB[i] = fmaf(s2, yA[i * 3 + 2], fmaf(c2, yA[i * 3 + 1], yA[i * 3]));
        float yC[3];
#pragma unroll
        for (int i = 0; i < 3; ++i)
            yC[i] = fmaf(s1, yB[i * 3 + 2], fmaf(c1, yB[i * 3 + 1], yB[i * 3]));
        float Z = fmaf(s0, yC[2], fmaf(c0, yC[1], yC[0]));

        float sg  = 1.f / (1.f + __expf(-kk * Z));
        float act = sc * sg - of;

        int ai2 = __float_as_int(act);
        float f  = __int_as_float(__builtin_amdgcn_update_dpp(0, ai2, 0x00, 0xf, 0xf, true));
        float ii = __int_as_float(__builtin_amdgcn_update_dpp(0, ai2, 0x55, 0xf, 0xf, true));
        float gg = __int_as_float(__builtin_amdgcn_update_dpp(0, ai2, 0xAA, 0xf, 0xf, true));
        float oo = __int_as_float(__builtin_amdgcn_update_dpp(0, ai2, 0xFF, 0xf, 0xf, true));

        cst = fmaf(f, cst, ii * gg);
        float tn = 2.f / (1.f + __expf(-2.f * cst)) - 1.f;
        float hme = oo * tn;

        if (g == 0) op[(size_t)sidx * 2048] = hme;

        int hi = __float_as_int(hme);
        hr0 = hme;
        hr1 = __int_as_float(__builtin_amdgcn_update_dpp(hi, hi, 0x124, 0xf, 0xf, false));
        hr2 = __int_as_float(__builtin_amdgcn_update_dpp(hi, hi, 0x128, 0xf, 0xf, false));
        hr3 = __int_as_float(__builtin_amdgcn_update_dpp(hi, hi, 0x12C, 0xf, 0xf, false));
    };

    for (int s = 0; s < S_LEN; s += 4) {
        step(A0, s);     A0 = *(const float4*)(ap + (size_t)((s + 4) & 255) * 8192);
        step(A1, s + 1); A1 = *(const float4*)(ap + (size_t)((s + 5) & 255) * 8192);
        step(A2, s + 2); A2 = *(const float4*)(ap + (size_t)((s + 6) & 255) * 8192);
        step(A3, s + 3); A3 = *(const float4*)(ap + (size_t)((s + 7) & 255) * 8192);
    }
}

// ---------------------------------------------------------------------------
// logits + log_softmax: wave per (s,b) row, lane = tag.
// ---------------------------------------------------------------------------
__global__ __launch_bounds__(256) void logits_kernel(const float* __restrict__ outs,
                                                     const float* __restrict__ tag_w,
                                                     const float* __restrict__ tag_b,
                                                     float* __restrict__ out) {
    int l = threadIdx.x & 63;
    int wid = (blockIdx.x * blockDim.x + threadIdx.x) >> 6;
    int nw  = (gridDim.x * blockDim.x) >> 6;

    float4 w = *(const float4*)(tag_w + l * 4);
    float bb = tag_b[l];

    for (int row = wid; row < ROWS; row += nw) {
        float4 h = *(const float4*)(outs + (size_t)row * 4);
        float z = fmaf(h.x, w.x, fmaf(h.y, w.y, fmaf(h.z, w.z, fmaf(h.w, w.w, bb))));
        float m = z;
#pragma unroll
        for (int d = 1; d < 64; d <<= 1) m = fmaxf(m, __shfl_xor(m, d, 64));
        float e = __expf(z - m);
        float ssum = e;
#pragma unroll
        for (int d = 1; d < 64; d <<= 1) ssum += __shfl_xor(ssum, d, 64);
        out[(size_t)row * 64 + l] = (z - m) - __logf(ssum);
    }
}

// ---------------------------------------------------------------------------
extern "C" void kernel_launch(void* const* d_in, const int* in_sizes, int n_in,
                              void* d_out, int out_size, void* d_ws, size_t ws_size,
                              hipStream_t stream) {
    const int*   sent  = (const int*)d_in[0];
    const float* emb   = (const float*)d_in[1];
    const float* lin_w = (const float*)d_in[2];
    const float* lin_b = (const float*)d_in[3];
    const float* qrx   = (const float*)d_in[4];
    const float* qry   = (const float*)d_in[5];
    const float* qrz   = (const float*)d_in[6];
    const float* qcrx  = (const float*)d_in[7];
    const float* tag_w = (const float*)d_in[8];
    const float* tag_b = (const float*)d_in[9];
    float* out = (float*)d_out;

    char* ws = (char*)d_ws;
    float*  Tg   = (float*)ws;                                    // 16*81*4 = 5184 B
    float*  angx = (float*)(ws + 8192);                           // ROWS*16*4 = 8 MB
    float*  outs = (float*)(ws + 8192 + (size_t)ROWS * 16 * 4);   // ROWS*4*4  = 2 MB

    setup_kernel<<<dim3(1), dim3(1024), 0, stream>>>(qrx, qry, qrz, qcrx, Tg);
    angx_kernel<<<dim3(1024), dim3(256), 0, stream>>>(sent, emb, lin_w, lin_b, angx);
    lstm_kernel<<<dim3(128), dim3(64), 0, stream>>>(lin_w, Tg, angx, outs);
    logits_kernel<<<dim3(1024), dim3(256), 0, stream>>>(outs, tag_w, tag_b, out);
}